// Round 9
// baseline (797.688 us; speedup 1.0000x reference)
//
#include <hip/hip_runtime.h>
#include <hip/hip_bf16.h>

typedef __bf16 bf16x8 __attribute__((ext_vector_type(8)));
typedef float  f32x4  __attribute__((ext_vector_type(4)));

// cheap activations: v_exp_f32 computes 2^x; rcp ~1ulp
__device__ __forceinline__ float fastsig(float x){
  return __builtin_amdgcn_rcpf(1.f + __builtin_amdgcn_exp2f(-1.4426950408889634f * x));
}
__device__ __forceinline__ float fasttanh(float x){
  return 1.f - 2.f * __builtin_amdgcn_rcpf(__builtin_amdgcn_exp2f(2.8853900817779268f * x) + 1.f);
}

// float <-> order-preserving unsigned for atomicMax on floats
__device__ __forceinline__ unsigned encf(float f){
  unsigned u = __float_as_uint(f);
  return (u & 0x80000000u) ? ~u : (u | 0x80000000u);
}
__device__ __forceinline__ float decf(unsigned u){
  return __uint_as_float((u & 0x80000000u) ? (u ^ 0x80000000u) : ~u);
}

// LDS swizzle for the GEMM tiles (128B rows)
__device__ __forceinline__ int swzG(int row, int byteoff){ return ((row<<7) + byteoff) ^ ((row & 7) << 4); }

// ---------------- fill ----------------
__global__ void fill_u32_kernel(unsigned* p, unsigned v, int n){
  int g = blockIdx.x*256 + threadIdx.x;
  if (g < n) p[g] = v;
}

// ---------------- weight prep ----------------
__global__ void prep_kernel(const float* __restrict__ Wih, const float* __restrict__ Whh,
                            const float* __restrict__ bih, const float* __restrict__ bhh,
                            const float* __restrict__ W1,
                            __bf16* __restrict__ Wcat, float* __restrict__ bias,
                            __bf16* __restrict__ W1b){
  int g = blockIdx.x*256 + threadIdx.x;
  if (g < 131072){
    int j = g >> 8, k = g & 255;
    float v = (k < 128) ? Wih[j*128 + k] : Whh[j*128 + (k-128)];
    Wcat[g] = (__bf16)v;
  } else if (g < 131584){
    int j = g - 131072;
    bias[j] = bih[j] + bhh[j];
  } else if (g < 164352){
    int q = g - 131584;
    W1b[q] = (__bf16)W1[q];
  }
}

// ---------------- gather + renorm (wave per row, 128-d rows) ----------------
__global__ void gather_renorm_kernel(const float* __restrict__ emb, const int* __restrict__ idxarr,
                                     __bf16* __restrict__ dst, int rows, int dstStride, int zeroFirst){
  int r = blockIdx.x*4 + (threadIdx.x >> 6);
  if (r >= rows) return;
  int lane = threadIdx.x & 63;
  int idx = idxarr ? idxarr[r] : (r + 1);
  float2 v = *(const float2*)(emb + (size_t)idx*128 + lane*2);
  float ss = v.x*v.x + v.y*v.y;
  #pragma unroll
  for (int m = 1; m < 64; m <<= 1) ss += __shfl_xor(ss, m);
  float scale = (ss > 1.f) ? (1.f/sqrtf(ss)) : 1.f;
  if (zeroFirst && idx == 0) scale = 0.f;
  __bf16* o = dst + (size_t)r*dstStride + lane*2;
  o[0] = (__bf16)(v.x*scale);
  o[1] = (__bf16)(v.y*scale);
}

// ---------------- persistent LSTM, M=64/block, 16 waves, W streamed from L2 ----------------
// 1024 threads = 16 waves: wave w -> dim group wv=w&7 (16 dims, all 4 gates), sample half sh=w>>3
// (2 sample tiles of 16). Per wave: 64 MFMA/step, acc 32 regs -> ~115 regs total => 4 waves/SIMD
// (2x r8's occupancy; r8 was latency-bound at 2 waves/SIMD: Mfma 22% VALU 33% Occ 18.5%).
// Swapped MFMA: gates^T = mfma(A=W rows, B=sample rows). c in regs; h lives in the A-tile.
// x pre-renormed from itn (bf16 copy). Single-buffered A-tile [64][x|h|pad]=33.8KB, 2 barriers/step.
// W: 2-slot register pipeline, 1 panel ahead. W traffic: 400x20x256KB = 2GB L2.
#define ROWB 528
__global__ __launch_bounds__(1024, 1)
void lstm_kernel(const __bf16* __restrict__ itn, const int* __restrict__ seqs,
                 const __bf16* __restrict__ Wcat, const float* __restrict__ bias,
                 const int* __restrict__ lens, __bf16* __restrict__ A1){
  __shared__ char Ab[64*ROWB];
  __shared__ float bsh[512];

  const int tid  = threadIdx.x;
  const int lane = tid & 63;
  const int w    = tid >> 6;   // 0..15
  const int wv   = w & 7;      // dim group
  const int sh   = w >> 3;     // sample half (tiles 2sh, 2sh+1)
  const int l15  = lane & 15;
  const int lq   = lane >> 4;  // 0..3
  const int n0   = blockIdx.x * 64;

  if (tid < 512) bsh[tid] = bias[tid];

  // W row pointers per gate; panel kk adds kk*32 elements (imm-foldable)
  const __bf16* wp[4];
  #pragma unroll
  for (int gi = 0; gi < 4; ++gi)
    wp[gi] = Wcat + (size_t)((gi*128 + wv*16 + l15)*256 + lq*8);

  // packed lens for this lane's 2 sample tiles
  int lens_p = lens[n0 + (sh*2)*16 + l15] | (lens[n0 + (sh*2+1)*16 + l15] << 8);

  float c[2][4];
  #pragma unroll
  for (int s = 0; s < 2; ++s)
    #pragma unroll
    for (int r = 0; r < 4; ++r) c[s][r] = 0.f;

  // loop-invariant LDS byte offsets
  int rbs[2], hws[2];
  #pragma unroll
  for (int s = 0; s < 2; ++s){
    rbs[s] = ((sh*2+s)*16 + l15)*ROWB + lq*16;                   // B-frag base (+kk*64)
    hws[s] = ((sh*2+s)*16 + l15)*ROWB + 256 + (wv*16 + lq*4)*2;  // h write (int2)
  }
  const int xrow = tid >> 4;          // 0..63 : staged row
  const int xsub = tid & 15;          // 16 threads/row, 16B each
  const int xwr  = xrow*ROWB + xsub*16;
  const int hwr  = xrow*ROWB + 256 + xsub*16;

  // ---- prologue: h=0, stage x0 (pre-renormed bf16 from itn) ----
  {
    const int4 z = {0,0,0,0};
    *(int4*)(Ab + hwr) = z;
    int idx0 = seqs[(n0 + xrow)*20 + 0];
    int4 a = z;
    if (idx0 > 0) a = *(const int4*)(itn + (size_t)(idx0-1)*128 + xsub*8);
    *(int4*)(Ab + xwr) = a;
  }
  int idx_next = seqs[(n0 + xrow)*20 + 1];
  __syncthreads();

  for (int t = 0; t < 20; ++t){
    // ---- issue x_{t+1} load (flies under the MFMA loop) ----
    int4 xq = {0,0,0,0};
    if (t < 19 && idx_next > 0)
      xq = *(const int4*)(itn + (size_t)(idx_next-1)*128 + xsub*8);
    if (t < 18) idx_next = seqs[(n0 + xrow)*20 + t + 2];

    // ---- acc init = bias (from LDS stash) ----
    f32x4 acc[2][4];   // [sample tile][gate]
    #pragma unroll
    for (int gi = 0; gi < 4; ++gi){
      f32x4 bv = *(const f32x4*)(bsh + gi*128 + wv*16 + lq*4);
      acc[0][gi] = bv; acc[1][gi] = bv;
    }

    // ---- MFMA loop, W 2-slot pipeline ----
    int4 s0[4], s1[4];
    #pragma unroll
    for (int gi = 0; gi < 4; ++gi) s0[gi] = *(const int4*)(wp[gi]);
    #pragma unroll
    for (int kk = 0; kk < 8; ++kk){
      if (kk < 7){
        if (kk & 1){
          #pragma unroll
          for (int gi = 0; gi < 4; ++gi) s0[gi] = *(const int4*)(wp[gi] + (kk+1)*32);
        } else {
          #pragma unroll
          for (int gi = 0; gi < 4; ++gi) s1[gi] = *(const int4*)(wp[gi] + (kk+1)*32);
        }
      }
      bf16x8 bfr[2];
      #pragma unroll
      for (int s = 0; s < 2; ++s)
        bfr[s] = __builtin_bit_cast(bf16x8, *(const int4*)(Ab + rbs[s] + kk*64));
      #pragma unroll
      for (int gi = 0; gi < 4; ++gi){
        bf16x8 wf = __builtin_bit_cast(bf16x8, (kk & 1) ? s1[gi] : s0[gi]);
        acc[0][gi] = __builtin_amdgcn_mfma_f32_16x16x32_bf16(wf, bfr[0], acc[0][gi], 0,0,0);
        acc[1][gi] = __builtin_amdgcn_mfma_f32_16x16x32_bf16(wf, bfr[1], acc[1][gi], 0,0,0);
      }
    }

    // ---- in-register cell update ----
    float hv[2][4];
    #pragma unroll
    for (int s = 0; s < 2; ++s){
      const bool up = t < ((lens_p >> (8*s)) & 255);
      #pragma unroll
      for (int r = 0; r < 4; ++r){
        float cn = fastsig(acc[s][1][r])*c[s][r] + fastsig(acc[s][0][r])*fasttanh(acc[s][2][r]);
        hv[s][r] = fastsig(acc[s][3][r])*fasttanh(cn);
        if (up) c[s][r] = cn;
      }
    }

    __syncthreads();   // barrier1: all A-tile reads of this step done

    // ---- conditional h writes (frozen lanes keep old h in LDS) ----
    #pragma unroll
    for (int s = 0; s < 2; ++s){
      if (t < ((lens_p >> (8*s)) & 255)){
        union { __bf16 h[4]; int2 q; } u;
        #pragma unroll
        for (int r = 0; r < 4; ++r) u.h[r] = (__bf16)hv[s][r];
        *(int2*)(Ab + hws[s]) = u.q;
      }
    }
    // ---- x_{t+1} write ----
    if (t < 19) *(int4*)(Ab + xwr) = xq;
    __syncthreads();   // barrier2: writes visible for step t+1
  }

  // ---- export hn from the A-tile (holds latest/frozen h) ----
  {
    int4 a = *(const int4*)(Ab + hwr);
    *(int4*)(A1 + (size_t)(n0 + xrow)*256 + 128 + xsub*8) = a;
  }
}

// ---------------- generic bf16 GEMM: C[M][N] = A[M][K] @ B[N][K]^T, f32 out ----------------
template<int RELU>
__global__ __launch_bounds__(256, 2)
void gemm_bt_kernel(const __bf16* __restrict__ A, const __bf16* __restrict__ B,
                    float* __restrict__ C, int M, int N, int K){
  __shared__ char As[16384];
  __shared__ char Bs[16384];
  const int tid  = threadIdx.x;
  const int lane = tid & 63;
  const int wv   = tid >> 6;
  const int wmw  = wv >> 1, wnw = wv & 1;
  const int l15  = lane & 15, lq = lane >> 4;
  const int n0 = blockIdx.x * 128;
  const int m0 = blockIdx.y * 128;

  f32x4 acc[4][4];
  #pragma unroll
  for (int a = 0; a < 4; ++a)
    #pragma unroll
    for (int b = 0; b < 4; ++b){ f32x4 z; z[0]=0.f;z[1]=0.f;z[2]=0.f;z[3]=0.f; acc[a][b]=z; }

  const int nkb = K >> 6;
  for (int kb = 0; kb < nkb; ++kb){
    __syncthreads();
    #pragma unroll
    for (int i = 0; i < 4; ++i){
      int c = tid + i*256;
      int row = c >> 3, kc = c & 7;
      int4 va = *(const int4*)(A + (size_t)(m0+row)*K + kb*64 + kc*8);
      *(int4*)(As + swzG(row, kc*16)) = va;
      int4 vb = {0,0,0,0};
      if (n0 + row < N) vb = *(const int4*)(B + (size_t)(n0+row)*K + kb*64 + kc*8);
      *(int4*)(Bs + swzG(row, kc*16)) = vb;
    }
    __syncthreads();
    #pragma unroll
    for (int ks = 0; ks < 2; ++ks){
      bf16x8 af[4], bfr[4];
      #pragma unroll
      for (int mi = 0; mi < 4; ++mi)
        af[mi] = __builtin_bit_cast(bf16x8, *(const int4*)(As + swzG(wmw*64 + mi*16 + l15, ks*64 + lq*16)));
      #pragma unroll
      for (int ni = 0; ni < 4; ++ni)
        bfr[ni] = __builtin_bit_cast(bf16x8, *(const int4*)(Bs + swzG(wnw*64 + ni*16 + l15, ks*64 + lq*16)));
      #pragma unroll
      for (int mi = 0; mi < 4; ++mi)
        #pragma unroll
        for (int ni = 0; ni < 4; ++ni)
          acc[mi][ni] = __builtin_amdgcn_mfma_f32_16x16x32_bf16(af[mi], bfr[ni], acc[mi][ni], 0,0,0);
    }
  }
  #pragma unroll
  for (int mi = 0; mi < 4; ++mi){
    #pragma unroll
    for (int ni = 0; ni < 4; ++ni){
      int col = n0 + wnw*64 + ni*16 + l15;
      if (col < N){
        #pragma unroll
        for (int r = 0; r < 4; ++r){
          int row = m0 + wmw*64 + mi*16 + lq*4 + r;
          float v = acc[mi][ni][r];
          if (RELU) v = fmaxf(v, 0.f);
          C[(size_t)row*N + col] = v;
        }
      }
    }
  }
}

// ---------------- feat[cur_sidx] = hn[cur_sidx] ----------------
__global__ void set_cur_kernel(const __bf16* __restrict__ A1, const int* __restrict__ cur_sidx,
                               float* __restrict__ feat){
  int g = blockIdx.x*256 + threadIdx.x;   // 512*128
  int i = g >> 7, d = g & 127;
  int row = cur_sidx[i];
  feat[(size_t)row*128 + d] = (float)A1[(size_t)row*256 + 128 + d];
}

// ---------------- GAT ----------------
__global__ void gat_score_kernel(const float* __restrict__ feat, const int* __restrict__ src,
                                 const int* __restrict__ dst, const int* __restrict__ idxm,
                                 float* __restrict__ score, unsigned* __restrict__ mbuf, int E){
  int e = blockIdx.x*4 + (threadIdx.x >> 6);
  if (e >= E) return;
  int lane = threadIdx.x & 63;
  int de = dst[e];
  const float2 a = *(const float2*)(feat + (size_t)src[e]*128 + lane*2);
  const float2 b = *(const float2*)(feat + (size_t)idxm[de]*128 + lane*2);
  float s = a.x*b.x + a.y*b.y;
  #pragma unroll
  for (int m = 1; m < 64; m <<= 1) s += __shfl_xor(s, m);
  if (lane == 0){
    score[e] = s;
    atomicMax(mbuf + de, encf(s));
  }
}

__global__ void gat_expsum_kernel(const float* __restrict__ score, const int* __restrict__ dst,
                                  const unsigned* __restrict__ mbuf, float* __restrict__ wbuf,
                                  float* __restrict__ z, int E){
  int e = blockIdx.x*256 + threadIdx.x;
  if (e >= E) return;
  int de = dst[e];
  float w = __expf(score[e] - decf(mbuf[de]));
  wbuf[e] = w;
  atomicAdd(z + de, w);
}

__global__ void gat_agg_kernel(const float* __restrict__ feat, const int* __restrict__ src,
                               const int* __restrict__ dst, const float* __restrict__ wbuf,
                               float* __restrict__ agg, int E){
  int g = blockIdx.x*256 + threadIdx.x;
  int e = g >> 7, d = g & 127;
  if (e >= E) return;
  atomicAdd(agg + (size_t)dst[e]*128 + d, wbuf[e] * feat[(size_t)src[e]*128 + d]);
}

// out[v][:] = featPrev[idxm[v]][:] + relu((agg[v]/max(z,eps)) @ gW^T + gb)
__global__ void gat_out_kernel(const float* __restrict__ featPrev, const int* __restrict__ idxm,
                               const float* __restrict__ agg, const float* __restrict__ z,
                               const float* __restrict__ gW, const float* __restrict__ gb,
                               float* __restrict__ out, int V){
  __shared__ float arow[128];
  int v = blockIdx.x;
  int d = threadIdx.x;   // 128 threads
  float zi = 1.f / fmaxf(z[v], 1e-12f);
  arow[d] = agg[(size_t)v*128 + d] * zi;
  __syncthreads();
  float s = gb[d];
  #pragma unroll 4
  for (int k = 0; k < 128; ++k) s += arow[k] * gW[d*128 + k];
  out[(size_t)v*128 + d] = featPrev[(size_t)idxm[v]*128 + d] + fmaxf(s, 0.f);
}

// ---------------- sr = concat(cur, feat2) @ W2^T (f32), store bf16 ----------------
__global__ void sr_kernel(const __bf16* __restrict__ A1, const float* __restrict__ feat2,
                          const int* __restrict__ cur_sidx, const float* __restrict__ W2,
                          __bf16* __restrict__ srb){
  __shared__ float cat[256];
  int i = blockIdx.x;
  int j = threadIdx.x;   // 128 threads
  int row = cur_sidx[i];
  cat[j]       = (float)A1[(size_t)row*256 + 128 + j];
  cat[128 + j] = feat2[(size_t)i*128 + j];
  __syncthreads();
  float s = 0.f;
  #pragma unroll 4
  for (int k = 0; k < 256; ++k) s += cat[k] * W2[j*256 + k];
  srb[(size_t)i*128 + j] = (__bf16)s;
}

// ---------------- launch ----------------
extern "C" void kernel_launch(void* const* d_in, const int* in_sizes, int n_in,
                              void* d_out, int out_size, void* d_ws, size_t ws_size,
                              hipStream_t stream){
  const float* user_emb = (const float*)d_in[0];
  const float* item_emb = (const float*)d_in[1];
  const float* Wih = (const float*)d_in[2];
  const float* Whh = (const float*)d_in[3];
  const float* bih = (const float*)d_in[4];
  const float* bhh = (const float*)d_in[5];
  const float* W1  = (const float*)d_in[6];
  const float* gW0 = (const float*)d_in[7];
  const float* gb0 = (const float*)d_in[8];
  const float* gW1 = (const float*)d_in[9];
  const float* gb1 = (const float*)d_in[10];
  const float* W2  = (const float*)d_in[11];
  const int* uids = (const int*)d_in[12];
  const int* seqs = (const int*)d_in[13];
  const int* lens = (const int*)d_in[14];
  const int* cur_sidx = (const int*)d_in[15];
  const int* src0 = (const int*)d_in[16];
  const int* dst0 = (const int*)d_in[17];
  const int* idx0 = (const int*)d_in[18];
  const int* src1 = (const int*)d_in[19];
  const int* dst1 = (const int*)d_in[20];
  const int* idx1 = (const int*)d_in[21];
  float* out = (float*)d_out;

  char* ws = (char*)d_ws;
  size_t off = 0;
  auto alloc = [&](size_t bytes)->char* {
    char* p = ws + off;
    off += (bytes + 255) & ~((size_t)255);
    return p;
  };
  __bf16*   A1    = (__bf16*)  alloc(25600u*256*2);   // [lt | hn] bf16
  __bf16*   Wcat  = (__bf16*)  alloc(512u*256*2);
  float*    bias  = (float*)   alloc(512u*4);
  __bf16*   W1b   = (__bf16*)  alloc(128u*256*2);
  float*    feat  = (float*)   alloc(25600u*128*4);
  float*    sc0   = (float*)   alloc(25600u*4);
  float*    w0    = (float*)   alloc(25600u*4);
  unsigned* m0    = (unsigned*)alloc(2560u*4);
  float*    z0    = (float*)   alloc(2560u*4);
  float*    agg0  = (float*)   alloc(2560u*128*4);
  float*    feat1 = (float*)   alloc(2560u*128*4);
  float*    sc1   = (float*)   alloc(5120u*4);
  float*    w1    = (float*)   alloc(5120u*4);
  unsigned* m1    = (unsigned*)alloc(512u*4);
  float*    z1    = (float*)   alloc(512u*4);
  float*    agg1  = (float*)   alloc(512u*128*4);
  float*    feat2 = (float*)   alloc(512u*128*4);
  __bf16*   srb   = (__bf16*)  alloc(512u*128*2);
  __bf16*   itn   = (__bf16*)  alloc(50000u*128*2);

  // prep + init
  prep_kernel<<<642, 256, 0, stream>>>(Wih, Whh, bih, bhh, W1, Wcat, bias, W1b);
  fill_u32_kernel<<<10,   256, 0, stream>>>((unsigned*)z0,   0u, 2560);
  fill_u32_kernel<<<1280, 256, 0, stream>>>((unsigned*)agg0, 0u, 327680);
  fill_u32_kernel<<<10,   256, 0, stream>>>(m0, 0x00800000u, 2560);   // enc(-FLT_MAX)
  fill_u32_kernel<<<2,    256, 0, stream>>>((unsigned*)z1,   0u, 512);
  fill_u32_kernel<<<256,  256, 0, stream>>>((unsigned*)agg1, 0u, 65536);
  fill_u32_kernel<<<2,    256, 0, stream>>>(m1, 0x00800000u, 512);

  // renorm(item_emb[1:]) -> bf16 (used by BOTH the LSTM x-staging and the logits GEMM)
  gather_renorm_kernel<<<12500, 256, 0, stream>>>(item_emb, nullptr, itn, 50000, 128, 0);

  // long_term = renorm(user_emb[uids]) -> A1[:,0:128]
  gather_renorm_kernel<<<6400, 256, 0, stream>>>(user_emb, uids, A1, 25600, 256, 0);

  // LSTM (x pre-renormed from itn); hn -> A1[:,128:256]
  lstm_kernel<<<400, 1024, 0, stream>>>(itn, seqs, Wcat, bias, lens, A1);

  // feat = relu(A1 @ W1^T)
  gemm_bt_kernel<1><<<dim3(1, 200), 256, 0, stream>>>(A1, W1b, feat, 25600, 128, 256);
  set_cur_kernel<<<256, 256, 0, stream>>>(A1, cur_sidx, feat);

  // GAT layer 0
  gat_score_kernel <<<6400, 256, 0, stream>>>(feat, src0, dst0, idx0, sc0, m0, 25600);
  gat_expsum_kernel<<<100,  256, 0, stream>>>(sc0, dst0, m0, w0, z0, 25600);
  gat_agg_kernel   <<<12800,256, 0, stream>>>(feat, src0, dst0, w0, agg0, 25600);
  gat_out_kernel   <<<2560, 128, 0, stream>>>(feat, idx0, agg0, z0, gW0, gb0, feat1, 2560);

  // GAT layer 1
  gat_score_kernel <<<1280, 256, 0, stream>>>(feat1, src1, dst1, idx1, sc1, m1, 5120);
  gat_expsum_kernel<<<20,   256, 0, stream>>>(sc1, dst1, m1, w1, z1, 5120);
  gat_agg_kernel   <<<2560, 256, 0, stream>>>(feat1, src1, dst1, w1, agg1, 5120);
  gat_out_kernel   <<<512,  128, 0, stream>>>(feat1, idx1, agg1, z1, gW1, gb1, feat2, 512);

  // sr = concat(cur, feat2) @ W2^T  (bf16 out for logits GEMM)
  sr_kernel<<<512, 128, 0, stream>>>(A1, feat2, cur_sidx, W2, srb);

  // logits = srb @ itn^T
  gemm_bt_kernel<0><<<dim3(391, 4), 256, 0, stream>>>(srb, itn, out, 512, 50000, 128);
}

// Round 10
// 441.476 us; speedup vs baseline: 1.8069x; 1.8069x over previous
//
#include <hip/hip_runtime.h>
#include <hip/hip_bf16.h>

typedef __bf16 bf16x8 __attribute__((ext_vector_type(8)));
typedef float  f32x4  __attribute__((ext_vector_type(4)));

// cheap activations: v_exp_f32 computes 2^x; rcp ~1ulp (validated r9: absmax unchanged)
__device__ __forceinline__ float fastsig(float x){
  return __builtin_amdgcn_rcpf(1.f + __builtin_amdgcn_exp2f(-1.4426950408889634f * x));
}
__device__ __forceinline__ float fasttanh(float x){
  return 1.f - 2.f * __builtin_amdgcn_rcpf(__builtin_amdgcn_exp2f(2.8853900817779268f * x) + 1.f);
}

// float <-> order-preserving unsigned for atomicMax on floats
__device__ __forceinline__ unsigned encf(float f){
  unsigned u = __float_as_uint(f);
  return (u & 0x80000000u) ? ~u : (u | 0x80000000u);
}
__device__ __forceinline__ float decf(unsigned u){
  return __uint_as_float((u & 0x80000000u) ? (u ^ 0x80000000u) : ~u);
}

// LDS swizzle for the GEMM tiles (128B rows)
__device__ __forceinline__ int swzG(int row, int byteoff){ return ((row<<7) + byteoff) ^ ((row & 7) << 4); }

// ---------------- fill ----------------
__global__ void fill_u32_kernel(unsigned* p, unsigned v, int n){
  int g = blockIdx.x*256 + threadIdx.x;
  if (g < n) p[g] = v;
}

// ---------------- length counting sort (20 bins) ----------------
__global__ void len_hist_kernel(const int* __restrict__ lens, int* __restrict__ hist, int n){
  int i = blockIdx.x*256 + threadIdx.x;
  if (i < n) atomicAdd(&hist[lens[i]-1], 1);
}
__global__ void len_prefix_kernel(const int* __restrict__ hist, int* __restrict__ offs){
  if (threadIdx.x == 0){
    int acc = 0;
    for (int i = 0; i < 20; ++i){ offs[i] = acc; acc += hist[i]; }
  }
}
__global__ void len_scatter_kernel(const int* __restrict__ lens, int* __restrict__ offs,
                                   int* __restrict__ perm, int n){
  int i = blockIdx.x*256 + threadIdx.x;
  if (i < n){
    int p = atomicAdd(&offs[lens[i]-1], 1);
    perm[p] = i;
  }
}

// ---------------- weight prep ----------------
__global__ void prep_kernel(const float* __restrict__ Wih, const float* __restrict__ Whh,
                            const float* __restrict__ bih, const float* __restrict__ bhh,
                            const float* __restrict__ W1,
                            __bf16* __restrict__ Wcat, float* __restrict__ bias,
                            __bf16* __restrict__ W1b){
  int g = blockIdx.x*256 + threadIdx.x;
  if (g < 131072){
    int j = g >> 8, k = g & 255;
    float v = (k < 128) ? Wih[j*128 + k] : Whh[j*128 + (k-128)];
    Wcat[g] = (__bf16)v;
  } else if (g < 131584){
    int j = g - 131072;
    bias[j] = bih[j] + bhh[j];
  } else if (g < 164352){
    int q = g - 131584;
    W1b[q] = (__bf16)W1[q];
  }
}

// ---------------- gather + renorm (wave per row, 128-d rows) ----------------
__global__ void gather_renorm_kernel(const float* __restrict__ emb, const int* __restrict__ idxarr,
                                     __bf16* __restrict__ dst, int rows, int dstStride, int zeroFirst){
  int r = blockIdx.x*4 + (threadIdx.x >> 6);
  if (r >= rows) return;
  int lane = threadIdx.x & 63;
  int idx = idxarr ? idxarr[r] : (r + 1);
  float2 v = *(const float2*)(emb + (size_t)idx*128 + lane*2);
  float ss = v.x*v.x + v.y*v.y;
  #pragma unroll
  for (int m = 1; m < 64; m <<= 1) ss += __shfl_xor(ss, m);
  float scale = (ss > 1.f) ? (1.f/sqrtf(ss)) : 1.f;
  if (zeroFirst && idx == 0) scale = 0.f;
  __bf16* o = dst + (size_t)r*dstStride + lane*2;
  o[0] = (__bf16)(v.x*scale);
  o[1] = (__bf16)(v.y*scale);
}

// ---------------- persistent LSTM, M=64/block (len-sorted), W streamed from L2 ----------------
// r8 structure (512 thr = 8 waves; wave wv owns dims wv*16..+15, all 4 gates; 4 sample tiles)
// + LENGTH SORT: block processes 64 samples of similar len (perm from counting sort) and loops
// only to the block's max len -> ~45% less work/W-traffic (lens ~ U[1,20], mean 10.5 vs 20).
// Swapped MFMA: gates^T = mfma(A=W rows, B=sample rows). c in regs; h lives in the A-tile.
// x pre-renormed from itn. Single-buffered A-tile [64][x|h|pad], 2 barriers/step.
// W: 2-slot register pipeline, 1 panel ahead. Export to A1[perm[i]] -> order-independent output.
#define ROWB 528
__global__ __launch_bounds__(512, 1)
void lstm_kernel(const __bf16* __restrict__ itn, const int* __restrict__ seqs,
                 const __bf16* __restrict__ Wcat, const float* __restrict__ bias,
                 const int* __restrict__ lens, const int* __restrict__ perm,
                 __bf16* __restrict__ A1){
  __shared__ char Ab[64*ROWB];
  __shared__ float bsh[512];
  __shared__ int   llen[64];

  const int tid  = threadIdx.x;
  const int lane = tid & 63;
  const int wv   = tid >> 6;   // 0..7 : dim group
  const int l15  = lane & 15;
  const int lq   = lane >> 4;  // 0..3
  const int n0   = blockIdx.x * 64;

  bsh[tid] = bias[tid];
  if (tid < 64) llen[tid] = lens[perm[n0 + tid]];

  // W row pointers per gate; panel kk adds kk*32 elements (imm-foldable)
  const __bf16* wp[4];
  #pragma unroll
  for (int gi = 0; gi < 4; ++gi)
    wp[gi] = Wcat + (size_t)((gi*128 + wv*16 + l15)*256 + lq*8);

  const int xrow = tid >> 3;          // 0..63 : staged row
  const int xsub = tid & 7;           // 8 threads/row, 32B each
  const int xwr  = xrow*ROWB + xsub*32;
  const int hwr  = xrow*ROWB + 256 + xsub*32;
  const int sidx = perm[n0 + xrow];   // global sample id for this staged row

  __syncthreads();   // llen/bsh visible

  // block max len (uniform across block) + packed per-lane lens for the 4 sample tiles
  int mxl = 0;
  #pragma unroll 8
  for (int i = 0; i < 64; ++i) mxl = max(mxl, llen[i]);
  int lens_p = 0;
  #pragma unroll
  for (int s = 0; s < 4; ++s)
    lens_p |= llen[s*16 + l15] << (8*s);

  float c[4][4];
  #pragma unroll
  for (int s = 0; s < 4; ++s)
    #pragma unroll
    for (int r = 0; r < 4; ++r) c[s][r] = 0.f;

  // loop-invariant LDS byte offsets
  int rbs[4], hws[4];
  #pragma unroll
  for (int s = 0; s < 4; ++s){
    rbs[s] = (s*16 + l15)*ROWB + lq*16;                   // B-frag base (+kk*64)
    hws[s] = (s*16 + l15)*ROWB + 256 + (wv*16 + lq*4)*2;  // h write (int2)
  }

  // ---- prologue: h=0, stage x0 (pre-renormed bf16 from itn) ----
  {
    const int4 z = {0,0,0,0};
    *(int4*)(Ab + hwr)      = z;
    *(int4*)(Ab + hwr + 16) = z;
    int idx0 = seqs[(size_t)sidx*20 + 0];
    int4 a = z, b = z;
    if (idx0 > 0){
      const __bf16* sp = itn + (size_t)(idx0-1)*128 + xsub*16;
      a = *(const int4*)(sp);
      b = *(const int4*)(sp + 8);
    }
    *(int4*)(Ab + xwr)      = a;
    *(int4*)(Ab + xwr + 16) = b;
  }
  int idx_next = seqs[(size_t)sidx*20 + 1];
  __syncthreads();

  for (int t = 0; t < mxl; ++t){
    // ---- issue x_{t+1} loads (fly under the MFMA loop) ----
    int4 xq0 = {0,0,0,0}, xq1 = {0,0,0,0};
    const bool stage_next = (t + 1 < mxl);
    if (stage_next && idx_next > 0){
      const __bf16* sp = itn + (size_t)(idx_next-1)*128 + xsub*16;
      xq0 = *(const int4*)(sp);
      xq1 = *(const int4*)(sp + 8);
    }
    if (t + 2 < 20) idx_next = seqs[(size_t)sidx*20 + t + 2];

    // ---- acc init = bias (from LDS stash) ----
    f32x4 acc[4][4];   // [sample tile][gate]
    #pragma unroll
    for (int gi = 0; gi < 4; ++gi){
      f32x4 bv = *(const f32x4*)(bsh + gi*128 + wv*16 + lq*4);
      #pragma unroll
      for (int s = 0; s < 4; ++s) acc[s][gi] = bv;
    }

    // ---- MFMA loop, W 2-slot pipeline ----
    int4 s0[4], s1[4];
    #pragma unroll
    for (int gi = 0; gi < 4; ++gi) s0[gi] = *(const int4*)(wp[gi]);
    #pragma unroll
    for (int kk = 0; kk < 8; ++kk){
      if (kk < 7){
        if (kk & 1){
          #pragma unroll
          for (int gi = 0; gi < 4; ++gi) s0[gi] = *(const int4*)(wp[gi] + (kk+1)*32);
        } else {
          #pragma unroll
          for (int gi = 0; gi < 4; ++gi) s1[gi] = *(const int4*)(wp[gi] + (kk+1)*32);
        }
      }
      bf16x8 bfr[4];
      #pragma unroll
      for (int s = 0; s < 4; ++s)
        bfr[s] = __builtin_bit_cast(bf16x8, *(const int4*)(Ab + rbs[s] + kk*64));
      #pragma unroll
      for (int gi = 0; gi < 4; ++gi){
        bf16x8 wf = __builtin_bit_cast(bf16x8, (kk & 1) ? s1[gi] : s0[gi]);
        #pragma unroll
        for (int s = 0; s < 4; ++s)
          acc[s][gi] = __builtin_amdgcn_mfma_f32_16x16x32_bf16(wf, bfr[s], acc[s][gi], 0,0,0);
      }
    }

    // ---- in-register cell update ----
    float hv[4][4];
    #pragma unroll
    for (int s = 0; s < 4; ++s){
      const bool up = t < ((lens_p >> (8*s)) & 255);
      #pragma unroll
      for (int r = 0; r < 4; ++r){
        float cn = fastsig(acc[s][1][r])*c[s][r] + fastsig(acc[s][0][r])*fasttanh(acc[s][2][r]);
        hv[s][r] = fastsig(acc[s][3][r])*fasttanh(cn);
        if (up) c[s][r] = cn;
      }
    }

    __syncthreads();   // barrier1: all A-tile reads of this step done

    // ---- conditional h writes (frozen lanes keep old h in LDS) ----
    #pragma unroll
    for (int s = 0; s < 4; ++s){
      if (t < ((lens_p >> (8*s)) & 255)){
        union { __bf16 h[4]; int2 q; } u;
        #pragma unroll
        for (int r = 0; r < 4; ++r) u.h[r] = (__bf16)hv[s][r];
        *(int2*)(Ab + hws[s]) = u.q;
      }
    }
    // ---- x_{t+1} write ----
    if (stage_next){
      *(int4*)(Ab + xwr)      = xq0;
      *(int4*)(Ab + xwr + 16) = xq1;
    }
    __syncthreads();   // barrier2: writes visible for step t+1
  }

  // ---- export hn from the A-tile (holds latest/frozen h) ----
  {
    int4 a = *(const int4*)(Ab + hwr);
    int4 b = *(const int4*)(Ab + hwr + 16);
    __bf16* op = A1 + (size_t)sidx*256 + 128 + xsub*16;
    *(int4*)(op)     = a;
    *(int4*)(op + 8) = b;
  }
}

// ---------------- generic bf16 GEMM: C[M][N] = A[M][K] @ B[N][K]^T, f32 out ----------------
template<int RELU>
__global__ __launch_bounds__(256, 2)
void gemm_bt_kernel(const __bf16* __restrict__ A, const __bf16* __restrict__ B,
                    float* __restrict__ C, int M, int N, int K){
  __shared__ char As[16384];
  __shared__ char Bs[16384];
  const int tid  = threadIdx.x;
  const int lane = tid & 63;
  const int wv   = tid >> 6;
  const int wmw  = wv >> 1, wnw = wv & 1;
  const int l15  = lane & 15, lq = lane >> 4;
  const int n0 = blockIdx.x * 128;
  const int m0 = blockIdx.y * 128;

  f32x4 acc[4][4];
  #pragma unroll
  for (int a = 0; a < 4; ++a)
    #pragma unroll
    for (int b = 0; b < 4; ++b){ f32x4 z; z[0]=0.f;z[1]=0.f;z[2]=0.f;z[3]=0.f; acc[a][b]=z; }

  const int nkb = K >> 6;
  for (int kb = 0; kb < nkb; ++kb){
    __syncthreads();
    #pragma unroll
    for (int i = 0; i < 4; ++i){
      int c = tid + i*256;
      int row = c >> 3, kc = c & 7;
      int4 va = *(const int4*)(A + (size_t)(m0+row)*K + kb*64 + kc*8);
      *(int4*)(As + swzG(row, kc*16)) = va;
      int4 vb = {0,0,0,0};
      if (n0 + row < N) vb = *(const int4*)(B + (size_t)(n0+row)*K + kb*64 + kc*8);
      *(int4*)(Bs + swzG(row, kc*16)) = vb;
    }
    __syncthreads();
    #pragma unroll
    for (int ks = 0; ks < 2; ++ks){
      bf16x8 af[4], bfr[4];
      #pragma unroll
      for (int mi = 0; mi < 4; ++mi)
        af[mi] = __builtin_bit_cast(bf16x8, *(const int4*)(As + swzG(wmw*64 + mi*16 + l15, ks*64 + lq*16)));
      #pragma unroll
      for (int ni = 0; ni < 4; ++ni)
        bfr[ni] = __builtin_bit_cast(bf16x8, *(const int4*)(Bs + swzG(wnw*64 + ni*16 + l15, ks*64 + lq*16)));
      #pragma unroll
      for (int mi = 0; mi < 4; ++mi)
        #pragma unroll
        for (int ni = 0; ni < 4; ++ni)
          acc[mi][ni] = __builtin_amdgcn_mfma_f32_16x16x32_bf16(af[mi], bfr[ni], acc[mi][ni], 0,0,0);
    }
  }
  #pragma unroll
  for (int mi = 0; mi < 4; ++mi){
    #pragma unroll
    for (int ni = 0; ni < 4; ++ni){
      int col = n0 + wnw*64 + ni*16 + l15;
      if (col < N){
        #pragma unroll
        for (int r = 0; r < 4; ++r){
          int row = m0 + wmw*64 + mi*16 + lq*4 + r;
          float v = acc[mi][ni][r];
          if (RELU) v = fmaxf(v, 0.f);
          C[(size_t)row*N + col] = v;
        }
      }
    }
  }
}

// ---------------- feat[cur_sidx] = hn[cur_sidx] ----------------
__global__ void set_cur_kernel(const __bf16* __restrict__ A1, const int* __restrict__ cur_sidx,
                               float* __restrict__ feat){
  int g = blockIdx.x*256 + threadIdx.x;   // 512*128
  int i = g >> 7, d = g & 127;
  int row = cur_sidx[i];
  feat[(size_t)row*128 + d] = (float)A1[(size_t)row*256 + 128 + d];
}

// ---------------- GAT ----------------
__global__ void gat_score_kernel(const float* __restrict__ feat, const int* __restrict__ src,
                                 const int* __restrict__ dst, const int* __restrict__ idxm,
                                 float* __restrict__ score, unsigned* __restrict__ mbuf, int E){
  int e = blockIdx.x*4 + (threadIdx.x >> 6);
  if (e >= E) return;
  int lane = threadIdx.x & 63;
  int de = dst[e];
  const float2 a = *(const float2*)(feat + (size_t)src[e]*128 + lane*2);
  const float2 b = *(const float2*)(feat + (size_t)idxm[de]*128 + lane*2);
  float s = a.x*b.x + a.y*b.y;
  #pragma unroll
  for (int m = 1; m < 64; m <<= 1) s += __shfl_xor(s, m);
  if (lane == 0){
    score[e] = s;
    atomicMax(mbuf + de, encf(s));
  }
}

__global__ void gat_expsum_kernel(const float* __restrict__ score, const int* __restrict__ dst,
                                  const unsigned* __restrict__ mbuf, float* __restrict__ wbuf,
                                  float* __restrict__ z, int E){
  int e = blockIdx.x*256 + threadIdx.x;
  if (e >= E) return;
  int de = dst[e];
  float w = __expf(score[e] - decf(mbuf[de]));
  wbuf[e] = w;
  atomicAdd(z + de, w);
}

__global__ void gat_agg_kernel(const float* __restrict__ feat, const int* __restrict__ src,
                               const int* __restrict__ dst, const float* __restrict__ wbuf,
                               float* __restrict__ agg, int E){
  int g = blockIdx.x*256 + threadIdx.x;
  int e = g >> 7, d = g & 127;
  if (e >= E) return;
  atomicAdd(agg + (size_t)dst[e]*128 + d, wbuf[e] * feat[(size_t)src[e]*128 + d]);
}

// out[v][:] = featPrev[idxm[v]][:] + relu((agg[v]/max(z,eps)) @ gW^T + gb)
__global__ void gat_out_kernel(const float* __restrict__ featPrev, const int* __restrict__ idxm,
                               const float* __restrict__ agg, const float* __restrict__ z,
                               const float* __restrict__ gW, const float* __restrict__ gb,
                               float* __restrict__ out, int V){
  __shared__ float arow[128];
  int v = blockIdx.x;
  int d = threadIdx.x;   // 128 threads
  float zi = 1.f / fmaxf(z[v], 1e-12f);
  arow[d] = agg[(size_t)v*128 + d] * zi;
  __syncthreads();
  float s = gb[d];
  #pragma unroll 4
  for (int k = 0; k < 128; ++k) s += arow[k] * gW[d*128 + k];
  out[(size_t)v*128 + d] = featPrev[(size_t)idxm[v]*128 + d] + fmaxf(s, 0.f);
}

// ---------------- sr = concat(cur, feat2) @ W2^T (f32), store bf16 ----------------
__global__ void sr_kernel(const __bf16* __restrict__ A1, const float* __restrict__ feat2,
                          const int* __restrict__ cur_sidx, const float* __restrict__ W2,
                          __bf16* __restrict__ srb){
  __shared__ float cat[256];
  int i = blockIdx.x;
  int j = threadIdx.x;   // 128 threads
  int row = cur_sidx[i];
  cat[j]       = (float)A1[(size_t)row*256 + 128 + j];
  cat[128 + j] = feat2[(size_t)i*128 + j];
  __syncthreads();
  float s = 0.f;
  #pragma unroll 4
  for (int k = 0; k < 256; ++k) s += cat[k] * W2[j*256 + k];
  srb[(size_t)i*128 + j] = (__bf16)s;
}

// ---------------- launch ----------------
extern "C" void kernel_launch(void* const* d_in, const int* in_sizes, int n_in,
                              void* d_out, int out_size, void* d_ws, size_t ws_size,
                              hipStream_t stream){
  const float* user_emb = (const float*)d_in[0];
  const float* item_emb = (const float*)d_in[1];
  const float* Wih = (const float*)d_in[2];
  const float* Whh = (const float*)d_in[3];
  const float* bih = (const float*)d_in[4];
  const float* bhh = (const float*)d_in[5];
  const float* W1  = (const float*)d_in[6];
  const float* gW0 = (const float*)d_in[7];
  const float* gb0 = (const float*)d_in[8];
  const float* gW1 = (const float*)d_in[9];
  const float* gb1 = (const float*)d_in[10];
  const float* W2  = (const float*)d_in[11];
  const int* uids = (const int*)d_in[12];
  const int* seqs = (const int*)d_in[13];
  const int* lens = (const int*)d_in[14];
  const int* cur_sidx = (const int*)d_in[15];
  const int* src0 = (const int*)d_in[16];
  const int* dst0 = (const int*)d_in[17];
  const int* idx0 = (const int*)d_in[18];
  const int* src1 = (const int*)d_in[19];
  const int* dst1 = (const int*)d_in[20];
  const int* idx1 = (const int*)d_in[21];
  float* out = (float*)d_out;

  char* ws = (char*)d_ws;
  size_t off = 0;
  auto alloc = [&](size_t bytes)->char* {
    char* p = ws + off;
    off += (bytes + 255) & ~((size_t)255);
    return p;
  };
  __bf16*   A1    = (__bf16*)  alloc(25600u*256*2);   // [lt | hn] bf16
  __bf16*   Wcat  = (__bf16*)  alloc(512u*256*2);
  float*    bias  = (float*)   alloc(512u*4);
  __bf16*   W1b   = (__bf16*)  alloc(128u*256*2);
  float*    feat  = (float*)   alloc(25600u*128*4);
  float*    sc0   = (float*)   alloc(25600u*4);
  float*    w0    = (float*)   alloc(25600u*4);
  unsigned* m0    = (unsigned*)alloc(2560u*4);
  float*    z0    = (float*)   alloc(2560u*4);
  float*    agg0  = (float*)   alloc(2560u*128*4);
  float*    feat1 = (float*)   alloc(2560u*128*4);
  float*    sc1   = (float*)   alloc(5120u*4);
  float*    w1    = (float*)   alloc(5120u*4);
  unsigned* m1    = (unsigned*)alloc(512u*4);
  float*    z1    = (float*)   alloc(512u*4);
  float*    agg1  = (float*)   alloc(512u*128*4);
  float*    feat2 = (float*)   alloc(512u*128*4);
  __bf16*   srb   = (__bf16*)  alloc(512u*128*2);
  __bf16*   itn   = (__bf16*)  alloc(50000u*128*2);
  int*      hist  = (int*)     alloc(20u*4);
  int*      offs  = (int*)     alloc(20u*4);
  int*      perm  = (int*)     alloc(25600u*4);

  // prep + init
  prep_kernel<<<642, 256, 0, stream>>>(Wih, Whh, bih, bhh, W1, Wcat, bias, W1b);
  fill_u32_kernel<<<10,   256, 0, stream>>>((unsigned*)z0,   0u, 2560);
  fill_u32_kernel<<<1280, 256, 0, stream>>>((unsigned*)agg0, 0u, 327680);
  fill_u32_kernel<<<10,   256, 0, stream>>>(m0, 0x00800000u, 2560);   // enc(-FLT_MAX)
  fill_u32_kernel<<<2,    256, 0, stream>>>((unsigned*)z1,   0u, 512);
  fill_u32_kernel<<<256,  256, 0, stream>>>((unsigned*)agg1, 0u, 65536);
  fill_u32_kernel<<<2,    256, 0, stream>>>(m1, 0x00800000u, 512);
  fill_u32_kernel<<<1,    256, 0, stream>>>((unsigned*)hist, 0u, 20);

  // length counting sort -> perm (ascending len)
  len_hist_kernel   <<<100, 256, 0, stream>>>(lens, hist, 25600);
  len_prefix_kernel <<<1,    64, 0, stream>>>(hist, offs);
  len_scatter_kernel<<<100, 256, 0, stream>>>(lens, offs, perm, 25600);

  // renorm(item_emb[1:]) -> bf16 (used by BOTH the LSTM x-staging and the logits GEMM)
  gather_renorm_kernel<<<12500, 256, 0, stream>>>(item_emb, nullptr, itn, 50000, 128, 0);

  // long_term = renorm(user_emb[uids]) -> A1[:,0:128]
  gather_renorm_kernel<<<6400, 256, 0, stream>>>(user_emb, uids, A1, 25600, 256, 0);

  // LSTM (len-sorted blocks; x pre-renormed from itn); hn -> A1[:,128:256]
  lstm_kernel<<<400, 512, 0, stream>>>(itn, seqs, Wcat, bias, lens, perm, A1);

  // feat = relu(A1 @ W1^T)
  gemm_bt_kernel<1><<<dim3(1, 200), 256, 0, stream>>>(A1, W1b, feat, 25600, 128, 256);
  set_cur_kernel<<<256, 256, 0, stream>>>(A1, cur_sidx, feat);

  // GAT layer 0
  gat_score_kernel <<<6400, 256, 0, stream>>>(feat, src0, dst0, idx0, sc0, m0, 25600);
  gat_expsum_kernel<<<100,  256, 0, stream>>>(sc0, dst0, m0, w0, z0, 25600);
  gat_agg_kernel   <<<12800,256, 0, stream>>>(feat, src0, dst0, w0, agg0, 25600);
  gat_out_kernel   <<<2560, 128, 0, stream>>>(feat, idx0, agg0, z0, gW0, gb0, feat1, 2560);

  // GAT layer 1
  gat_score_kernel <<<1280, 256, 0, stream>>>(feat1, src1, dst1, idx1, sc1, m1, 5120);
  gat_expsum_kernel<<<20,   256, 0, stream>>>(sc1, dst1, m1, w1, z1, 5120);
  gat_agg_kernel   <<<2560, 256, 0, stream>>>(feat1, src1, dst1, w1, agg1, 5120);
  gat_out_kernel   <<<512,  128, 0, stream>>>(feat1, idx1, agg1, z1, gW1, gb1, feat2, 512);

  // sr = concat(cur, feat2) @ W2^T  (bf16 out for logits GEMM)
  sr_kernel<<<512, 128, 0, stream>>>(A1, feat2, cur_sidx, W2, srb);

  // logits = srb @ itn^T
  gemm_bt_kernel<0><<<dim3(391, 4), 256, 0, stream>>>(srb, itn, out, 512, 50000, 128);
}

// Round 12
// 389.472 us; speedup vs baseline: 2.0481x; 1.1335x over previous
//
#include <hip/hip_runtime.h>
#include <hip/hip_bf16.h>

typedef __bf16 bf16x8 __attribute__((ext_vector_type(8)));
typedef float  f32x4  __attribute__((ext_vector_type(4)));

// cheap activations: v_exp_f32 computes 2^x; rcp ~1ulp (validated: absmax unchanged since r7)
__device__ __forceinline__ float fastsig(float x){
  return __builtin_amdgcn_rcpf(1.f + __builtin_amdgcn_exp2f(-1.4426950408889634f * x));
}
__device__ __forceinline__ float fasttanh(float x){
  return 1.f - 2.f * __builtin_amdgcn_rcpf(__builtin_amdgcn_exp2f(2.8853900817779268f * x) + 1.f);
}

// float <-> order-preserving unsigned for atomicMax on floats
__device__ __forceinline__ unsigned encf(float f){
  unsigned u = __float_as_uint(f);
  return (u & 0x80000000u) ? ~u : (u | 0x80000000u);
}
__device__ __forceinline__ float decf(unsigned u){
  return __uint_as_float((u & 0x80000000u) ? (u ^ 0x80000000u) : ~u);
}

// LDS swizzle for the GEMM tiles (128B rows)
__device__ __forceinline__ int swzG(int row, int byteoff){ return ((row<<7) + byteoff) ^ ((row & 7) << 4); }

// ---------------- single fused init (replaces 7 fill launches) ----------------
// segments: agg0[327680]f32=0 | agg1[65536]f32=0 | z0[2560]f32=0 | z1[512]f32=0 |
//           m0[2560]u32=enc(-FLT_MAX) | m1[512]u32=enc(-FLT_MAX) | hist[20]=0
// total = 399380 elements -> grid 1561x256 (r11 crash: 1559 blocks left hist uninitialized)
__global__ void init_kernel(unsigned* agg0, unsigned* agg1, unsigned* z0, unsigned* z1,
                            unsigned* m0, unsigned* m1, unsigned* hist){
  int g = blockIdx.x*256 + threadIdx.x;
  if      (g < 327680)                          agg0[g] = 0u;
  else if ((g -= 327680) < 65536)               agg1[g] = 0u;
  else if ((g -= 65536)  < 2560)                z0[g]   = 0u;
  else if ((g -= 2560)   < 512)                 z1[g]   = 0u;
  else if ((g -= 512)    < 2560)                m0[g]   = 0x00800000u;
  else if ((g -= 2560)   < 512)                 m1[g]   = 0x00800000u;
  else if ((g -= 512)    < 20)                  hist[g] = 0u;
}

// ---------------- length counting sort (20 bins, DESCENDING for LPT schedule) ----------------
__global__ void len_hist_kernel(const int* __restrict__ lens, int* __restrict__ hist, int n){
  int i = blockIdx.x*256 + threadIdx.x;
  if (i < n) atomicAdd(&hist[lens[i]-1], 1);
}
__global__ void len_prefix_kernel(const int* __restrict__ hist, int* __restrict__ offs){
  if (threadIdx.x == 0){
    int acc = 0;
    for (int i = 19; i >= 0; --i){ offs[i] = acc; acc += hist[i]; }   // longest first
  }
}
__global__ void len_scatter_kernel(const int* __restrict__ lens, int* __restrict__ offs,
                                   int* __restrict__ perm, int n){
  int i = blockIdx.x*256 + threadIdx.x;
  if (i < n){
    int p = atomicAdd(&offs[lens[i]-1], 1);
    perm[p] = i;
  }
}

// ---------------- weight prep ----------------
__global__ void prep_kernel(const float* __restrict__ Wih, const float* __restrict__ Whh,
                            const float* __restrict__ bih, const float* __restrict__ bhh,
                            const float* __restrict__ W1,
                            __bf16* __restrict__ Wcat, float* __restrict__ bias,
                            __bf16* __restrict__ W1b){
  int g = blockIdx.x*256 + threadIdx.x;
  if (g < 131072){
    int j = g >> 8, k = g & 255;
    float v = (k < 128) ? Wih[j*128 + k] : Whh[j*128 + (k-128)];
    Wcat[g] = (__bf16)v;
  } else if (g < 131584){
    int j = g - 131072;
    bias[j] = bih[j] + bhh[j];
  } else if (g < 164352){
    int q = g - 131584;
    W1b[q] = (__bf16)W1[q];
  }
}

// ---------------- gather + renorm (wave per row, 128-d rows) ----------------
__global__ void gather_renorm_kernel(const float* __restrict__ emb, const int* __restrict__ idxarr,
                                     __bf16* __restrict__ dst, int rows, int dstStride, int zeroFirst){
  int r = blockIdx.x*4 + (threadIdx.x >> 6);
  if (r >= rows) return;
  int lane = threadIdx.x & 63;
  int idx = idxarr ? idxarr[r] : (r + 1);
  float2 v = *(const float2*)(emb + (size_t)idx*128 + lane*2);
  float ss = v.x*v.x + v.y*v.y;
  #pragma unroll
  for (int m = 1; m < 64; m <<= 1) ss += __shfl_xor(ss, m);
  float scale = (ss > 1.f) ? (1.f/sqrtf(ss)) : 1.f;
  if (zeroFirst && idx == 0) scale = 0.f;
  __bf16* o = dst + (size_t)r*dstStride + lane*2;
  o[0] = (__bf16)(v.x*scale);
  o[1] = (__bf16)(v.y*scale);
}

// ---------------- persistent LSTM, M=64/block (len-sorted DESC), W streamed from L2 ----------------
// r8 structure (512 thr = 8 waves; wave wv owns dims wv*16..+15, all 4 gates; 4 sample tiles)
// + DESCENDING length sort (LPT): longest blocks dispatch first -> short blocks backfill,
// killing r10's tail (ascending put all len-20 blocks in the final partial wave of 144 CUs).
// Block loops to its max len = llen[0] (descending order within grid).
// Swapped MFMA: gates^T = mfma(A=W rows, B=sample rows). c in regs; h lives in the A-tile.
// x pre-renormed from itn. Single-buffered A-tile [64][x|h|pad], 2 barriers/step.
// W: 2-slot register pipeline, 1 panel ahead. Export to A1[perm[i]] -> order-independent output.
#define ROWB 528
__global__ __launch_bounds__(512, 1)
void lstm_kernel(const __bf16* __restrict__ itn, const int* __restrict__ seqs,
                 const __bf16* __restrict__ Wcat, const float* __restrict__ bias,
                 const int* __restrict__ lens, const int* __restrict__ perm,
                 __bf16* __restrict__ A1){
  __shared__ char Ab[64*ROWB];
  __shared__ float bsh[512];
  __shared__ int   llen[64];

  const int tid  = threadIdx.x;
  const int lane = tid & 63;
  const int wv   = tid >> 6;   // 0..7 : dim group
  const int l15  = lane & 15;
  const int lq   = lane >> 4;  // 0..3
  const int n0   = blockIdx.x * 64;

  bsh[tid] = bias[tid];
  if (tid < 64) llen[tid] = lens[perm[n0 + tid]];

  // W row pointers per gate; panel kk adds kk*32 elements (imm-foldable)
  const __bf16* wp[4];
  #pragma unroll
  for (int gi = 0; gi < 4; ++gi)
    wp[gi] = Wcat + (size_t)((gi*128 + wv*16 + l15)*256 + lq*8);

  const int xrow = tid >> 3;          // 0..63 : staged row
  const int xsub = tid & 7;           // 8 threads/row, 32B each
  const int xwr  = xrow*ROWB + xsub*32;
  const int hwr  = xrow*ROWB + 256 + xsub*32;
  const int sidx = perm[n0 + xrow];   // global sample id for this staged row

  __syncthreads();   // llen/bsh visible

  const int mxl = llen[0];   // descending order: first row has the block max
  int lens_p = 0;
  #pragma unroll
  for (int s = 0; s < 4; ++s)
    lens_p |= llen[s*16 + l15] << (8*s);

  float c[4][4];
  #pragma unroll
  for (int s = 0; s < 4; ++s)
    #pragma unroll
    for (int r = 0; r < 4; ++r) c[s][r] = 0.f;

  // loop-invariant LDS byte offsets
  int rbs[4], hws[4];
  #pragma unroll
  for (int s = 0; s < 4; ++s){
    rbs[s] = (s*16 + l15)*ROWB + lq*16;                   // B-frag base (+kk*64)
    hws[s] = (s*16 + l15)*ROWB + 256 + (wv*16 + lq*4)*2;  // h write (int2)
  }

  // ---- prologue: h=0, stage x0 (pre-renormed bf16 from itn) ----
  {
    const int4 z = {0,0,0,0};
    *(int4*)(Ab + hwr)      = z;
    *(int4*)(Ab + hwr + 16) = z;
    int idx0 = seqs[(size_t)sidx*20 + 0];
    int4 a = z, b = z;
    if (idx0 > 0){
      const __bf16* sp = itn + (size_t)(idx0-1)*128 + xsub*16;
      a = *(const int4*)(sp);
      b = *(const int4*)(sp + 8);
    }
    *(int4*)(Ab + xwr)      = a;
    *(int4*)(Ab + xwr + 16) = b;
  }
  int idx_next = seqs[(size_t)sidx*20 + 1];
  __syncthreads();

  for (int t = 0; t < mxl; ++t){
    // ---- issue x_{t+1} loads (fly under the MFMA loop) ----
    int4 xq0 = {0,0,0,0}, xq1 = {0,0,0,0};
    const bool stage_next = (t + 1 < mxl);
    if (stage_next && idx_next > 0){
      const __bf16* sp = itn + (size_t)(idx_next-1)*128 + xsub*16;
      xq0 = *(const int4*)(sp);
      xq1 = *(const int4*)(sp + 8);
    }
    if (t + 2 < 20) idx_next = seqs[(size_t)sidx*20 + t + 2];

    // ---- acc init = bias (from LDS stash) ----
    f32x4 acc[4][4];   // [sample tile][gate]
    #pragma unroll
    for (int gi = 0; gi < 4; ++gi){
      f32x4 bv = *(const f32x4*)(bsh + gi*128 + wv*16 + lq*4);
      #pragma unroll
      for (int s = 0; s < 4; ++s) acc[s][gi] = bv;
    }

    // ---- MFMA loop, W 2-slot pipeline ----
    int4 s0[4], s1[4];
    #pragma unroll
    for (int gi = 0; gi < 4; ++gi) s0[gi] = *(const int4*)(wp[gi]);
    #pragma unroll
    for (int kk = 0; kk < 8; ++kk){
      if (kk < 7){
        if (kk & 1){
          #pragma unroll
          for (int gi = 0; gi < 4; ++gi) s0[gi] = *(const int4*)(wp[gi] + (kk+1)*32);
        } else {
          #pragma unroll
          for (int gi = 0; gi < 4; ++gi) s1[gi] = *(const int4*)(wp[gi] + (kk+1)*32);
        }
      }
      bf16x8 bfr[4];
      #pragma unroll
      for (int s = 0; s < 4; ++s)
        bfr[s] = __builtin_bit_cast(bf16x8, *(const int4*)(Ab + rbs[s] + kk*64));
      #pragma unroll
      for (int gi = 0; gi < 4; ++gi){
        bf16x8 wf = __builtin_bit_cast(bf16x8, (kk & 1) ? s1[gi] : s0[gi]);
        #pragma unroll
        for (int s = 0; s < 4; ++s)
          acc[s][gi] = __builtin_amdgcn_mfma_f32_16x16x32_bf16(wf, bfr[s], acc[s][gi], 0,0,0);
      }
    }

    // ---- in-register cell update ----
    float hv[4][4];
    #pragma unroll
    for (int s = 0; s < 4; ++s){
      const bool up = t < ((lens_p >> (8*s)) & 255);
      #pragma unroll
      for (int r = 0; r < 4; ++r){
        float cn = fastsig(acc[s][1][r])*c[s][r] + fastsig(acc[s][0][r])*fasttanh(acc[s][2][r]);
        hv[s][r] = fastsig(acc[s][3][r])*fasttanh(cn);
        if (up) c[s][r] = cn;
      }
    }

    __syncthreads();   // barrier1: all A-tile reads of this step done

    // ---- conditional h writes (frozen lanes keep old h in LDS) ----
    #pragma unroll
    for (int s = 0; s < 4; ++s){
      if (t < ((lens_p >> (8*s)) & 255)){
        union { __bf16 h[4]; int2 q; } u;
        #pragma unroll
        for (int r = 0; r < 4; ++r) u.h[r] = (__bf16)hv[s][r];
        *(int2*)(Ab + hws[s]) = u.q;
      }
    }
    // ---- x_{t+1} write ----
    if (stage_next){
      *(int4*)(Ab + xwr)      = xq0;
      *(int4*)(Ab + xwr + 16) = xq1;
    }
    __syncthreads();   // barrier2: writes visible for step t+1
  }

  // ---- export hn from the A-tile (holds latest/frozen h) ----
  {
    int4 a = *(const int4*)(Ab + hwr);
    int4 b = *(const int4*)(Ab + hwr + 16);
    __bf16* op = A1 + (size_t)sidx*256 + 128 + xsub*16;
    *(int4*)(op)     = a;
    *(int4*)(op + 8) = b;
  }
}

// ---------------- generic bf16 GEMM: C[M][N] = A[M][K] @ B[N][K]^T, f32 out ----------------
template<int RELU>
__global__ __launch_bounds__(256, 2)
void gemm_bt_kernel(const __bf16* __restrict__ A, const __bf16* __restrict__ B,
                    float* __restrict__ C, int M, int N, int K){
  __shared__ char As[16384];
  __shared__ char Bs[16384];
  const int tid  = threadIdx.x;
  const int lane = tid & 63;
  const int wv   = tid >> 6;
  const int wmw  = wv >> 1, wnw = wv & 1;
  const int l15  = lane & 15, lq = lane >> 4;
  const int n0 = blockIdx.x * 128;
  const int m0 = blockIdx.y * 128;

  f32x4 acc[4][4];
  #pragma unroll
  for (int a = 0; a < 4; ++a)
    #pragma unroll
    for (int b = 0; b < 4; ++b){ f32x4 z; z[0]=0.f;z[1]=0.f;z[2]=0.f;z[3]=0.f; acc[a][b]=z; }

  const int nkb = K >> 6;
  for (int kb = 0; kb < nkb; ++kb){
    __syncthreads();
    #pragma unroll
    for (int i = 0; i < 4; ++i){
      int c = tid + i*256;
      int row = c >> 3, kc = c & 7;
      int4 va = *(const int4*)(A + (size_t)(m0+row)*K + kb*64 + kc*8);
      *(int4*)(As + swzG(row, kc*16)) = va;
      int4 vb = {0,0,0,0};
      if (n0 + row < N) vb = *(const int4*)(B + (size_t)(n0+row)*K + kb*64 + kc*8);
      *(int4*)(Bs + swzG(row, kc*16)) = vb;
    }
    __syncthreads();
    #pragma unroll
    for (int ks = 0; ks < 2; ++ks){
      bf16x8 af[4], bfr[4];
      #pragma unroll
      for (int mi = 0; mi < 4; ++mi)
        af[mi] = __builtin_bit_cast(bf16x8, *(const int4*)(As + swzG(wmw*64 + mi*16 + l15, ks*64 + lq*16)));
      #pragma unroll
      for (int ni = 0; ni < 4; ++ni)
        bfr[ni] = __builtin_bit_cast(bf16x8, *(const int4*)(Bs + swzG(wnw*64 + ni*16 + l15, ks*64 + lq*16)));
      #pragma unroll
      for (int mi = 0; mi < 4; ++mi)
        #pragma unroll
        for (int ni = 0; ni < 4; ++ni)
          acc[mi][ni] = __builtin_amdgcn_mfma_f32_16x16x32_bf16(af[mi], bfr[ni], acc[mi][ni], 0,0,0);
    }
  }
  #pragma unroll
  for (int mi = 0; mi < 4; ++mi){
    #pragma unroll
    for (int ni = 0; ni < 4; ++ni){
      int col = n0 + wnw*64 + ni*16 + l15;
      if (col < N){
        #pragma unroll
        for (int r = 0; r < 4; ++r){
          int row = m0 + wmw*64 + mi*16 + lq*4 + r;
          float v = acc[mi][ni][r];
          if (RELU) v = fmaxf(v, 0.f);
          C[(size_t)row*N + col] = v;
        }
      }
    }
  }
}

// ---------------- feat[cur_sidx] = hn[cur_sidx] ----------------
__global__ void set_cur_kernel(const __bf16* __restrict__ A1, const int* __restrict__ cur_sidx,
                               float* __restrict__ feat){
  int g = blockIdx.x*256 + threadIdx.x;   // 512*128
  int i = g >> 7, d = g & 127;
  int row = cur_sidx[i];
  feat[(size_t)row*128 + d] = (float)A1[(size_t)row*256 + 128 + d];
}

// ---------------- GAT ----------------
__global__ void gat_score_kernel(const float* __restrict__ feat, const int* __restrict__ src,
                                 const int* __restrict__ dst, const int* __restrict__ idxm,
                                 float* __restrict__ score, unsigned* __restrict__ mbuf, int E){
  int e = blockIdx.x*4 + (threadIdx.x >> 6);
  if (e >= E) return;
  int lane = threadIdx.x & 63;
  int de = dst[e];
  const float2 a = *(const float2*)(feat + (size_t)src[e]*128 + lane*2);
  const float2 b = *(const float2*)(feat + (size_t)idxm[de]*128 + lane*2);
  float s = a.x*b.x + a.y*b.y;
  #pragma unroll
  for (int m = 1; m < 64; m <<= 1) s += __shfl_xor(s, m);
  if (lane == 0){
    score[e] = s;
    atomicMax(mbuf + de, encf(s));
  }
}

// fused expsum+agg: each (e,d) recomputes w = exp(score-m); lane d==0 also accumulates z
__global__ void gat_agg_kernel(const float* __restrict__ feat, const int* __restrict__ src,
                               const int* __restrict__ dst, const float* __restrict__ score,
                               const unsigned* __restrict__ mbuf,
                               float* __restrict__ agg, float* __restrict__ z, int E){
  int g = blockIdx.x*256 + threadIdx.x;
  int e = g >> 7, d = g & 127;
  if (e >= E) return;
  int de = dst[e];
  float w = __expf(score[e] - decf(mbuf[de]));
  if (d == 0) atomicAdd(z + de, w);
  atomicAdd(agg + (size_t)de*128 + d, w * feat[(size_t)src[e]*128 + d]);
}

// out[v][:] = featPrev[idxm[v]][:] + relu((agg[v]/max(z,eps)) @ gW^T + gb)
__global__ void gat_out_kernel(const float* __restrict__ featPrev, const int* __restrict__ idxm,
                               const float* __restrict__ agg, const float* __restrict__ z,
                               const float* __restrict__ gW, const float* __restrict__ gb,
                               float* __restrict__ out, int V){
  __shared__ float arow[128];
  int v = blockIdx.x;
  int d = threadIdx.x;   // 128 threads
  float zi = 1.f / fmaxf(z[v], 1e-12f);
  arow[d] = agg[(size_t)v*128 + d] * zi;
  __syncthreads();
  float s = gb[d];
  #pragma unroll 4
  for (int k = 0; k < 128; ++k) s += arow[k] * gW[d*128 + k];
  out[(size_t)v*128 + d] = featPrev[(size_t)idxm[v]*128 + d] + fmaxf(s, 0.f);
}

// ---------------- sr = concat(cur, feat2) @ W2^T (f32), store bf16 ----------------
__global__ void sr_kernel(const __bf16* __restrict__ A1, const float* __restrict__ feat2,
                          const int* __restrict__ cur_sidx, const float* __restrict__ W2,
                          __bf16* __restrict__ srb){
  __shared__ float cat[256];
  int i = blockIdx.x;
  int j = threadIdx.x;   // 128 threads
  int row = cur_sidx[i];
  cat[j]       = (float)A1[(size_t)row*256 + 128 + j];
  cat[128 + j] = feat2[(size_t)i*128 + j];
  __syncthreads();
  float s = 0.f;
  #pragma unroll 4
  for (int k = 0; k < 256; ++k) s += cat[k] * W2[j*256 + k];
  srb[(size_t)i*128 + j] = (__bf16)s;
}

// ---------------- launch ----------------
extern "C" void kernel_launch(void* const* d_in, const int* in_sizes, int n_in,
                              void* d_out, int out_size, void* d_ws, size_t ws_size,
                              hipStream_t stream){
  const float* user_emb = (const float*)d_in[0];
  const float* item_emb = (const float*)d_in[1];
  const float* Wih = (const float*)d_in[2];
  const float* Whh = (const float*)d_in[3];
  const float* bih = (const float*)d_in[4];
  const float* bhh = (const float*)d_in[5];
  const float* W1  = (const float*)d_in[6];
  const float* gW0 = (const float*)d_in[7];
  const float* gb0 = (const float*)d_in[8];
  const float* gW1 = (const float*)d_in[9];
  const float* gb1 = (const float*)d_in[10];
  const float* W2  = (const float*)d_in[11];
  const int* uids = (const int*)d_in[12];
  const int* seqs = (const int*)d_in[13];
  const int* lens = (const int*)d_in[14];
  const int* cur_sidx = (const int*)d_in[15];
  const int* src0 = (const int*)d_in[16];
  const int* dst0 = (const int*)d_in[17];
  const int* idx0 = (const int*)d_in[18];
  const int* src1 = (const int*)d_in[19];
  const int* dst1 = (const int*)d_in[20];
  const int* idx1 = (const int*)d_in[21];
  float* out = (float*)d_out;

  char* ws = (char*)d_ws;
  size_t off = 0;
  auto alloc = [&](size_t bytes)->char* {
    char* p = ws + off;
    off += (bytes + 255) & ~((size_t)255);
    return p;
  };
  __bf16*   A1    = (__bf16*)  alloc(25600u*256*2);   // [lt | hn] bf16
  __bf16*   Wcat  = (__bf16*)  alloc(512u*256*2);
  float*    bias  = (float*)   alloc(512u*4);
  __bf16*   W1b   = (__bf16*)  alloc(128u*256*2);
  float*    feat  = (float*)   alloc(25600u*128*4);
  float*    sc0   = (float*)   alloc(25600u*4);
  unsigned* m0    = (unsigned*)alloc(2560u*4);
  float*    z0    = (float*)   alloc(2560u*4);
  float*    agg0  = (float*)   alloc(2560u*128*4);
  float*    feat1 = (float*)   alloc(2560u*128*4);
  float*    sc1   = (float*)   alloc(5120u*4);
  unsigned* m1    = (unsigned*)alloc(512u*4);
  float*    z1    = (float*)   alloc(512u*4);
  float*    agg1  = (float*)   alloc(512u*128*4);
  float*    feat2 = (float*)   alloc(512u*128*4);
  __bf16*   srb   = (__bf16*)  alloc(512u*128*2);
  __bf16*   itn   = (__bf16*)  alloc(50000u*128*2);
  int*      hist  = (int*)     alloc(20u*4);
  int*      offs  = (int*)     alloc(20u*4);
  int*      perm  = (int*)     alloc(25600u*4);

  // prep + fused init (agg0|agg1|z0|z1|m0|m1|hist = 399380 elems -> 1561 blocks)
  prep_kernel<<<642, 256, 0, stream>>>(Wih, Whh, bih, bhh, W1, Wcat, bias, W1b);
  init_kernel<<<1561, 256, 0, stream>>>((unsigned*)agg0, (unsigned*)agg1, (unsigned*)z0,
                                        (unsigned*)z1, m0, m1, (unsigned*)hist);

  // length counting sort -> perm (DESCENDING len: LPT schedule)
  len_hist_kernel   <<<100, 256, 0, stream>>>(lens, hist, 25600);
  len_prefix_kernel <<<1,    64, 0, stream>>>(hist, offs);
  len_scatter_kernel<<<100, 256, 0, stream>>>(lens, offs, perm, 25600);

  // renorm(item_emb[1:]) -> bf16 (used by BOTH the LSTM x-staging and the logits GEMM)
  gather_renorm_kernel<<<12500, 256, 0, stream>>>(item_emb, nullptr, itn, 50000, 128, 0);

  // long_term = renorm(user_emb[uids]) -> A1[:,0:128]
  gather_renorm_kernel<<<6400, 256, 0, stream>>>(user_emb, uids, A1, 25600, 256, 0);

  // LSTM (len-sorted desc blocks; x pre-renormed from itn); hn -> A1[:,128:256]
  lstm_kernel<<<400, 512, 0, stream>>>(itn, seqs, Wcat, bias, lens, perm, A1);

  // feat = relu(A1 @ W1^T)
  gemm_bt_kernel<1><<<dim3(1, 200), 256, 0, stream>>>(A1, W1b, feat, 25600, 128, 256);
  set_cur_kernel<<<256, 256, 0, stream>>>(A1, cur_sidx, feat);

  // GAT layer 0
  gat_score_kernel<<<6400, 256, 0, stream>>>(feat, src0, dst0, idx0, sc0, m0, 25600);
  gat_agg_kernel  <<<12800,256, 0, stream>>>(feat, src0, dst0, sc0, m0, agg0, z0, 25600);
  gat_out_kernel  <<<2560, 128, 0, stream>>>(feat, idx0, agg0, z0, gW0, gb0, feat1, 2560);

  // GAT layer 1
  gat_score_kernel<<<1280, 256, 0, stream>>>(feat1, src1, dst1, idx1, sc1, m1, 5120);
  gat_agg_kernel  <<<2560, 256, 0, stream>>>(feat1, src1, dst1, sc1, m1, agg1, z1, 5120);
  gat_out_kernel  <<<512,  128, 0, stream>>>(feat1, idx1, agg1, z1, gW1, gb1, feat2, 512);

  // sr = concat(cur, feat2) @ W2^T  (bf16 out for logits GEMM)
  sr_kernel<<<512, 128, 0, stream>>>(A1, feat2, cur_sidx, W2, srb);

  // logits = srb @ itn^T
  gemm_bt_kernel<0><<<dim3(391, 4), 256, 0, stream>>>(srb, itn, out, 512, 50000, 128);
}

// Round 13
// 265.062 us; speedup vs baseline: 3.0094x; 1.4694x over previous
//
#include <hip/hip_runtime.h>
#include <hip/hip_bf16.h>

typedef __bf16 bf16x8 __attribute__((ext_vector_type(8)));
typedef float  f32x4  __attribute__((ext_vector_type(4)));

// cheap activations: v_exp_f32 computes 2^x; rcp ~1ulp (validated: absmax unchanged since r7)
__device__ __forceinline__ float fastsig(float x){
  return __builtin_amdgcn_rcpf(1.f + __builtin_amdgcn_exp2f(-1.4426950408889634f * x));
}
__device__ __forceinline__ float fasttanh(float x){
  return 1.f - 2.f * __builtin_amdgcn_rcpf(__builtin_amdgcn_exp2f(2.8853900817779268f * x) + 1.f);
}

// float <-> order-preserving unsigned for atomicMax on floats
__device__ __forceinline__ unsigned encf(float f){
  unsigned u = __float_as_uint(f);
  return (u & 0x80000000u) ? ~u : (u | 0x80000000u);
}
__device__ __forceinline__ float decf(unsigned u){
  return __uint_as_float((u & 0x80000000u) ? (u ^ 0x80000000u) : ~u);
}

// LDS swizzle for the GEMM tiles (128B rows)
__device__ __forceinline__ int swzG(int row, int byteoff){ return ((row<<7) + byteoff) ^ ((row & 7) << 4); }

// ---------------- single fused init ----------------
// segments: agg0[327680]f32=0 | agg1[65536]f32=0 | z0[2560]f32=0 | z1[512]f32=0 |
//           m0[2560]u32=enc(-FLT_MAX) | m1[512]u32=enc(-FLT_MAX) | hist[20]=0
// total = 399380 elements -> grid 1561x256
__global__ void init_kernel(unsigned* agg0, unsigned* agg1, unsigned* z0, unsigned* z1,
                            unsigned* m0, unsigned* m1, unsigned* hist){
  int g = blockIdx.x*256 + threadIdx.x;
  if      (g < 327680)                          agg0[g] = 0u;
  else if ((g -= 327680) < 65536)               agg1[g] = 0u;
  else if ((g -= 65536)  < 2560)                z0[g]   = 0u;
  else if ((g -= 2560)   < 512)                 z1[g]   = 0u;
  else if ((g -= 512)    < 2560)                m0[g]   = 0x00800000u;
  else if ((g -= 2560)   < 512)                 m1[g]   = 0x00800000u;
  else if ((g -= 512)    < 20)                  hist[g] = 0u;
}

// ---------------- length counting sort (20 bins, DESC for LPT), LDS-decontended ----------------
// r12 lesson: 25600 global atomicAdds onto 20 words serialize ~1280-way. LDS histogram first,
// then <=20 global atomics per block (100 blocks -> ~2000 total).
__global__ void len_hist_kernel(const int* __restrict__ lens, int* __restrict__ hist, int n){
  __shared__ int lh[20];
  int t = threadIdx.x;
  if (t < 20) lh[t] = 0;
  __syncthreads();
  int i = blockIdx.x*256 + t;
  if (i < n) atomicAdd(&lh[lens[i]-1], 1);
  __syncthreads();
  if (t < 20 && lh[t] > 0) atomicAdd(&hist[t], lh[t]);
}
__global__ void len_prefix_kernel(const int* __restrict__ hist, int* __restrict__ offs){
  if (threadIdx.x == 0){
    int acc = 0;
    for (int i = 19; i >= 0; --i){ offs[i] = acc; acc += hist[i]; }   // longest first
  }
}
// block-local rank via LDS counters; one global base-claim per (block,bin)
__global__ void len_scatter_kernel(const int* __restrict__ lens, int* __restrict__ offs,
                                   int* __restrict__ perm, int n){
  __shared__ int cnt[20];
  __shared__ int base[20];
  int t = threadIdx.x;
  if (t < 20) cnt[t] = 0;
  __syncthreads();
  int i = blockIdx.x*256 + t;
  int bin = 0, rank = 0;
  if (i < n){
    bin = lens[i] - 1;
    rank = atomicAdd(&cnt[bin], 1);
  }
  __syncthreads();
  if (t < 20 && cnt[t] > 0) base[t] = atomicAdd(&offs[t], cnt[t]);
  __syncthreads();
  if (i < n) perm[base[bin] + rank] = i;
}

// ---------------- weight prep ----------------
__global__ void prep_kernel(const float* __restrict__ Wih, const float* __restrict__ Whh,
                            const float* __restrict__ bih, const float* __restrict__ bhh,
                            const float* __restrict__ W1,
                            __bf16* __restrict__ Wcat, float* __restrict__ bias,
                            __bf16* __restrict__ W1b){
  int g = blockIdx.x*256 + threadIdx.x;
  if (g < 131072){
    int j = g >> 8, k = g & 255;
    float v = (k < 128) ? Wih[j*128 + k] : Whh[j*128 + (k-128)];
    Wcat[g] = (__bf16)v;
  } else if (g < 131584){
    int j = g - 131072;
    bias[j] = bih[j] + bhh[j];
  } else if (g < 164352){
    int q = g - 131584;
    W1b[q] = (__bf16)W1[q];
  }
}

// ---------------- fused gather+renorm: itn (50000 rows) + long_term (25600 rows) ----------------
// wave per row; rows [0,50000) -> itn[r] = renorm(item_emb[r+1]);
// rows [50000,75600) -> A1[i*256 + 0:128] = renorm(user_emb[uids[i]])
__global__ void gather2_kernel(const float* __restrict__ item_emb, const float* __restrict__ user_emb,
                               const int* __restrict__ uids,
                               __bf16* __restrict__ itn, __bf16* __restrict__ A1){
  int r = blockIdx.x*4 + (threadIdx.x >> 6);
  if (r >= 75600) return;
  int lane = threadIdx.x & 63;
  const float* src;
  __bf16* dst;
  if (r < 50000){
    src = item_emb + (size_t)(r + 1)*128;
    dst = itn + (size_t)r*128;
  } else {
    int i = r - 50000;
    src = user_emb + (size_t)uids[i]*128;
    dst = A1 + (size_t)i*256;
  }
  float2 v = *(const float2*)(src + lane*2);
  float ss = v.x*v.x + v.y*v.y;
  #pragma unroll
  for (int m = 1; m < 64; m <<= 1) ss += __shfl_xor(ss, m);
  float scale = (ss > 1.f) ? (1.f/sqrtf(ss)) : 1.f;
  dst[lane*2]     = (__bf16)(v.x*scale);
  dst[lane*2 + 1] = (__bf16)(v.y*scale);
}

// ---------------- persistent LSTM, M=64/block (len-sorted DESC), W streamed from L2 ----------------
// 512 thr = 8 waves; wave wv owns dims wv*16..+15, all 4 gates; 4 sample tiles of 16.
// DESC length sort (LPT): longest blocks dispatch first; block loops to llen[0].
// Swapped MFMA: gates^T = mfma(A=W rows, B=sample rows). c in regs; h lives in the A-tile.
// x pre-renormed from itn. Single-buffered A-tile [64][x|h|pad], 2 barriers/step.
// W: 2-slot register pipeline, 1 panel ahead. Export to A1[perm[i]] -> order-independent output.
#define ROWB 528
__global__ __launch_bounds__(512, 1)
void lstm_kernel(const __bf16* __restrict__ itn, const int* __restrict__ seqs,
                 const __bf16* __restrict__ Wcat, const float* __restrict__ bias,
                 const int* __restrict__ lens, const int* __restrict__ perm,
                 __bf16* __restrict__ A1){
  __shared__ char Ab[64*ROWB];
  __shared__ float bsh[512];
  __shared__ int   llen[64];

  const int tid  = threadIdx.x;
  const int lane = tid & 63;
  const int wv   = tid >> 6;   // 0..7 : dim group
  const int l15  = lane & 15;
  const int lq   = lane >> 4;  // 0..3
  const int n0   = blockIdx.x * 64;

  bsh[tid] = bias[tid];
  if (tid < 64) llen[tid] = lens[perm[n0 + tid]];

  // W row pointers per gate; panel kk adds kk*32 elements (imm-foldable)
  const __bf16* wp[4];
  #pragma unroll
  for (int gi = 0; gi < 4; ++gi)
    wp[gi] = Wcat + (size_t)((gi*128 + wv*16 + l15)*256 + lq*8);

  const int xrow = tid >> 3;          // 0..63 : staged row
  const int xsub = tid & 7;           // 8 threads/row, 32B each
  const int xwr  = xrow*ROWB + xsub*32;
  const int hwr  = xrow*ROWB + 256 + xsub*32;
  const int sidx = perm[n0 + xrow];   // global sample id for this staged row

  __syncthreads();   // llen/bsh visible

  const int mxl = llen[0];   // descending order: first row has the block max
  int lens_p = 0;
  #pragma unroll
  for (int s = 0; s < 4; ++s)
    lens_p |= llen[s*16 + l15] << (8*s);

  float c[4][4];
  #pragma unroll
  for (int s = 0; s < 4; ++s)
    #pragma unroll
    for (int r = 0; r < 4; ++r) c[s][r] = 0.f;

  // loop-invariant LDS byte offsets
  int rbs[4], hws[4];
  #pragma unroll
  for (int s = 0; s < 4; ++s){
    rbs[s] = (s*16 + l15)*ROWB + lq*16;                   // B-frag base (+kk*64)
    hws[s] = (s*16 + l15)*ROWB + 256 + (wv*16 + lq*4)*2;  // h write (int2)
  }

  // ---- prologue: h=0, stage x0 (pre-renormed bf16 from itn) ----
  {
    const int4 z = {0,0,0,0};
    *(int4*)(Ab + hwr)      = z;
    *(int4*)(Ab + hwr + 16) = z;
    int idx0 = seqs[(size_t)sidx*20 + 0];
    int4 a = z, b = z;
    if (idx0 > 0){
      const __bf16* sp = itn + (size_t)(idx0-1)*128 + xsub*16;
      a = *(const int4*)(sp);
      b = *(const int4*)(sp + 8);
    }
    *(int4*)(Ab + xwr)      = a;
    *(int4*)(Ab + xwr + 16) = b;
  }
  int idx_next = seqs[(size_t)sidx*20 + 1];
  __syncthreads();

  for (int t = 0; t < mxl; ++t){
    // ---- issue x_{t+1} loads (fly under the MFMA loop) ----
    int4 xq0 = {0,0,0,0}, xq1 = {0,0,0,0};
    const bool stage_next = (t + 1 < mxl);
    if (stage_next && idx_next > 0){
      const __bf16* sp = itn + (size_t)(idx_next-1)*128 + xsub*16;
      xq0 = *(const int4*)(sp);
      xq1 = *(const int4*)(sp + 8);
    }
    if (t + 2 < 20) idx_next = seqs[(size_t)sidx*20 + t + 2];

    // ---- acc init = bias (from LDS stash) ----
    f32x4 acc[4][4];   // [sample tile][gate]
    #pragma unroll
    for (int gi = 0; gi < 4; ++gi){
      f32x4 bv = *(const f32x4*)(bsh + gi*128 + wv*16 + lq*4);
      #pragma unroll
      for (int s = 0; s < 4; ++s) acc[s][gi] = bv;
    }

    // ---- MFMA loop, W 2-slot pipeline ----
    int4 s0[4], s1[4];
    #pragma unroll
    for (int gi = 0; gi < 4; ++gi) s0[gi] = *(const int4*)(wp[gi]);
    #pragma unroll
    for (int kk = 0; kk < 8; ++kk){
      if (kk < 7){
        if (kk & 1){
          #pragma unroll
          for (int gi = 0; gi < 4; ++gi) s0[gi] = *(const int4*)(wp[gi] + (kk+1)*32);
        } else {
          #pragma unroll
          for (int gi = 0; gi < 4; ++gi) s1[gi] = *(const int4*)(wp[gi] + (kk+1)*32);
        }
      }
      bf16x8 bfr[4];
      #pragma unroll
      for (int s = 0; s < 4; ++s)
        bfr[s] = __builtin_bit_cast(bf16x8, *(const int4*)(Ab + rbs[s] + kk*64));
      #pragma unroll
      for (int gi = 0; gi < 4; ++gi){
        bf16x8 wf = __builtin_bit_cast(bf16x8, (kk & 1) ? s1[gi] : s0[gi]);
        #pragma unroll
        for (int s = 0; s < 4; ++s)
          acc[s][gi] = __builtin_amdgcn_mfma_f32_16x16x32_bf16(wf, bfr[s], acc[s][gi], 0,0,0);
      }
    }

    // ---- in-register cell update ----
    float hv[4][4];
    #pragma unroll
    for (int s = 0; s < 4; ++s){
      const bool up = t < ((lens_p >> (8*s)) & 255);
      #pragma unroll
      for (int r = 0; r < 4; ++r){
        float cn = fastsig(acc[s][1][r])*c[s][r] + fastsig(acc[s][0][r])*fasttanh(acc[s][2][r]);
        hv[s][r] = fastsig(acc[s][3][r])*fasttanh(cn);
        if (up) c[s][r] = cn;
      }
    }

    __syncthreads();   // barrier1: all A-tile reads of this step done

    // ---- conditional h writes (frozen lanes keep old h in LDS) ----
    #pragma unroll
    for (int s = 0; s < 4; ++s){
      if (t < ((lens_p >> (8*s)) & 255)){
        union { __bf16 h[4]; int2 q; } u;
        #pragma unroll
        for (int r = 0; r < 4; ++r) u.h[r] = (__bf16)hv[s][r];
        *(int2*)(Ab + hws[s]) = u.q;
      }
    }
    // ---- x_{t+1} write ----
    if (stage_next){
      *(int4*)(Ab + xwr)      = xq0;
      *(int4*)(Ab + xwr + 16) = xq1;
    }
    __syncthreads();   // barrier2: writes visible for step t+1
  }

  // ---- export hn from the A-tile (holds latest/frozen h) ----
  {
    int4 a = *(const int4*)(Ab + hwr);
    int4 b = *(const int4*)(Ab + hwr + 16);
    __bf16* op = A1 + (size_t)sidx*256 + 128 + xsub*16;
    *(int4*)(op)     = a;
    *(int4*)(op + 8) = b;
  }
}

// ---------------- generic bf16 GEMM: C[M][N] = A[M][K] @ B[N][K]^T, f32 out ----------------
template<int RELU>
__global__ __launch_bounds__(256, 2)
void gemm_bt_kernel(const __bf16* __restrict__ A, const __bf16* __restrict__ B,
                    float* __restrict__ C, int M, int N, int K){
  __shared__ char As[16384];
  __shared__ char Bs[16384];
  const int tid  = threadIdx.x;
  const int lane = tid & 63;
  const int wv   = tid >> 6;
  const int wmw  = wv >> 1, wnw = wv & 1;
  const int l15  = lane & 15, lq = lane >> 4;
  const int n0 = blockIdx.x * 128;
  const int m0 = blockIdx.y * 128;

  f32x4 acc[4][4];
  #pragma unroll
  for (int a = 0; a < 4; ++a)
    #pragma unroll
    for (int b = 0; b < 4; ++b){ f32x4 z; z[0]=0.f;z[1]=0.f;z[2]=0.f;z[3]=0.f; acc[a][b]=z; }

  const int nkb = K >> 6;
  for (int kb = 0; kb < nkb; ++kb){
    __syncthreads();
    #pragma unroll
    for (int i = 0; i < 4; ++i){
      int c = tid + i*256;
      int row = c >> 3, kc = c & 7;
      int4 va = *(const int4*)(A + (size_t)(m0+row)*K + kb*64 + kc*8);
      *(int4*)(As + swzG(row, kc*16)) = va;
      int4 vb = {0,0,0,0};
      if (n0 + row < N) vb = *(const int4*)(B + (size_t)(n0+row)*K + kb*64 + kc*8);
      *(int4*)(Bs + swzG(row, kc*16)) = vb;
    }
    __syncthreads();
    #pragma unroll
    for (int ks = 0; ks < 2; ++ks){
      bf16x8 af[4], bfr[4];
      #pragma unroll
      for (int mi = 0; mi < 4; ++mi)
        af[mi] = __builtin_bit_cast(bf16x8, *(const int4*)(As + swzG(wmw*64 + mi*16 + l15, ks*64 + lq*16)));
      #pragma unroll
      for (int ni = 0; ni < 4; ++ni)
        bfr[ni] = __builtin_bit_cast(bf16x8, *(const int4*)(Bs + swzG(wnw*64 + ni*16 + l15, ks*64 + lq*16)));
      #pragma unroll
      for (int mi = 0; mi < 4; ++mi)
        #pragma unroll
        for (int ni = 0; ni < 4; ++ni)
          acc[mi][ni] = __builtin_amdgcn_mfma_f32_16x16x32_bf16(af[mi], bfr[ni], acc[mi][ni], 0,0,0);
    }
  }
  #pragma unroll
  for (int mi = 0; mi < 4; ++mi){
    #pragma unroll
    for (int ni = 0; ni < 4; ++ni){
      int col = n0 + wnw*64 + ni*16 + l15;
      if (col < N){
        #pragma unroll
        for (int r = 0; r < 4; ++r){
          int row = m0 + wmw*64 + mi*16 + lq*4 + r;
          float v = acc[mi][ni][r];
          if (RELU) v = fmaxf(v, 0.f);
          C[(size_t)row*N + col] = v;
        }
      }
    }
  }
}

// ---------------- feat[cur_sidx] = hn[cur_sidx] ----------------
__global__ void set_cur_kernel(const __bf16* __restrict__ A1, const int* __restrict__ cur_sidx,
                               float* __restrict__ feat){
  int g = blockIdx.x*256 + threadIdx.x;   // 512*128
  int i = g >> 7, d = g & 127;
  int row = cur_sidx[i];
  feat[(size_t)row*128 + d] = (float)A1[(size_t)row*256 + 128 + d];
}

// ---------------- GAT ----------------
__global__ void gat_score_kernel(const float* __restrict__ feat, const int* __restrict__ src,
                                 const int* __restrict__ dst, const int* __restrict__ idxm,
                                 float* __restrict__ score, unsigned* __restrict__ mbuf, int E){
  int e = blockIdx.x*4 + (threadIdx.x >> 6);
  if (e >= E) return;
  int lane = threadIdx.x & 63;
  int de = dst[e];
  const float2 a = *(const float2*)(feat + (size_t)src[e]*128 + lane*2);
  const float2 b = *(const float2*)(feat + (size_t)idxm[de]*128 + lane*2);
  float s = a.x*b.x + a.y*b.y;
  #pragma unroll
  for (int m = 1; m < 64; m <<= 1) s += __shfl_xor(s, m);
  if (lane == 0){
    score[e] = s;
    atomicMax(mbuf + de, encf(s));
  }
}

// fused expsum+agg: each (e,d) recomputes w = exp(score-m); lane d==0 also accumulates z
__global__ void gat_agg_kernel(const float* __restrict__ feat, const int* __restrict__ src,
                               const int* __restrict__ dst, const float* __restrict__ score,
                               const unsigned* __restrict__ mbuf,
                               float* __restrict__ agg, float* __restrict__ z, int E){
  int g = blockIdx.x*256 + threadIdx.x;
  int e = g >> 7, d = g & 127;
  if (e >= E) return;
  int de = dst[e];
  float w = __expf(score[e] - decf(mbuf[de]));
  if (d == 0) atomicAdd(z + de, w);
  atomicAdd(agg + (size_t)de*128 + d, w * feat[(size_t)src[e]*128 + d]);
}

// out[v][:] = featPrev[idxm[v]][:] + relu((agg[v]/max(z,eps)) @ gW^T + gb)
__global__ void gat_out_kernel(const float* __restrict__ featPrev, const int* __restrict__ idxm,
                               const float* __restrict__ agg, const float* __restrict__ z,
                               const float* __restrict__ gW, const float* __restrict__ gb,
                               float* __restrict__ out, int V){
  __shared__ float arow[128];
  int v = blockIdx.x;
  int d = threadIdx.x;   // 128 threads
  float zi = 1.f / fmaxf(z[v], 1e-12f);
  arow[d] = agg[(size_t)v*128 + d] * zi;
  __syncthreads();
  float s = gb[d];
  #pragma unroll 4
  for (int k = 0; k < 128; ++k) s += arow[k] * gW[d*128 + k];
  out[(size_t)v*128 + d] = featPrev[(size_t)idxm[v]*128 + d] + fmaxf(s, 0.f);
}

// ---------------- sr = concat(cur, feat2) @ W2^T (f32), store bf16 ----------------
__global__ void sr_kernel(const __bf16* __restrict__ A1, const float* __restrict__ feat2,
                          const int* __restrict__ cur_sidx, const float* __restrict__ W2,
                          __bf16* __restrict__ srb){
  __shared__ float cat[256];
  int i = blockIdx.x;
  int j = threadIdx.x;   // 128 threads
  int row = cur_sidx[i];
  cat[j]       = (float)A1[(size_t)row*256 + 128 + j];
  cat[128 + j] = feat2[(size_t)i*128 + j];
  __syncthreads();
  float s = 0.f;
  #pragma unroll 4
  for (int k = 0; k < 256; ++k) s += cat[k] * W2[j*256 + k];
  srb[(size_t)i*128 + j] = (__bf16)s;
}

// ---------------- launch ----------------
extern "C" void kernel_launch(void* const* d_in, const int* in_sizes, int n_in,
                              void* d_out, int out_size, void* d_ws, size_t ws_size,
                              hipStream_t stream){
  const float* user_emb = (const float*)d_in[0];
  const float* item_emb = (const float*)d_in[1];
  const float* Wih = (const float*)d_in[2];
  const float* Whh = (const float*)d_in[3];
  const float* bih = (const float*)d_in[4];
  const float* bhh = (const float*)d_in[5];
  const float* W1  = (const float*)d_in[6];
  const float* gW0 = (const float*)d_in[7];
  const float* gb0 = (const float*)d_in[8];
  const float* gW1 = (const float*)d_in[9];
  const float* gb1 = (const float*)d_in[10];
  const float* W2  = (const float*)d_in[11];
  const int* uids = (const int*)d_in[12];
  const int* seqs = (const int*)d_in[13];
  const int* lens = (const int*)d_in[14];
  const int* cur_sidx = (const int*)d_in[15];
  const int* src0 = (const int*)d_in[16];
  const int* dst0 = (const int*)d_in[17];
  const int* idx0 = (const int*)d_in[18];
  const int* src1 = (const int*)d_in[19];
  const int* dst1 = (const int*)d_in[20];
  const int* idx1 = (const int*)d_in[21];
  float* out = (float*)d_out;

  char* ws = (char*)d_ws;
  size_t off = 0;
  auto alloc = [&](size_t bytes)->char* {
    char* p = ws + off;
    off += (bytes + 255) & ~((size_t)255);
    return p;
  };
  __bf16*   A1    = (__bf16*)  alloc(25600u*256*2);   // [lt | hn] bf16
  __bf16*   Wcat  = (__bf16*)  alloc(512u*256*2);
  float*    bias  = (float*)   alloc(512u*4);
  __bf16*   W1b   = (__bf16*)  alloc(128u*256*2);
  float*    feat  = (float*)   alloc(25600u*128*4);
  float*    sc0   = (float*)   alloc(25600u*4);
  unsigned* m0    = (unsigned*)alloc(2560u*4);
  float*    z0    = (float*)   alloc(2560u*4);
  float*    agg0  = (float*)   alloc(2560u*128*4);
  float*    feat1 = (float*)   alloc(2560u*128*4);
  float*    sc1   = (float*)   alloc(5120u*4);
  unsigned* m1    = (unsigned*)alloc(512u*4);
  float*    z1    = (float*)   alloc(512u*4);
  float*    agg1  = (float*)   alloc(512u*128*4);
  float*    feat2 = (float*)   alloc(512u*128*4);
  __bf16*   srb   = (__bf16*)  alloc(512u*128*2);
  __bf16*   itn   = (__bf16*)  alloc(50000u*128*2);
  int*      hist  = (int*)     alloc(20u*4);
  int*      offs  = (int*)     alloc(20u*4);
  int*      perm  = (int*)     alloc(25600u*4);

  // prep + fused init (agg0|agg1|z0|z1|m0|m1|hist = 399380 elems -> 1561 blocks)
  prep_kernel<<<642, 256, 0, stream>>>(Wih, Whh, bih, bhh, W1, Wcat, bias, W1b);
  init_kernel<<<1561, 256, 0, stream>>>((unsigned*)agg0, (unsigned*)agg1, (unsigned*)z0,
                                        (unsigned*)z1, m0, m1, (unsigned*)hist);

  // length counting sort -> perm (DESCENDING len, LDS-decontended)
  len_hist_kernel   <<<100, 256, 0, stream>>>(lens, hist, 25600);
  len_prefix_kernel <<<1,    64, 0, stream>>>(hist, offs);
  len_scatter_kernel<<<100, 256, 0, stream>>>(lens, offs, perm, 25600);

  // fused gather+renorm: itn (item_emb[1:]) + long_term (user_emb[uids]) -> A1[:,0:128]
  gather2_kernel<<<18900, 256, 0, stream>>>(item_emb, user_emb, uids, itn, A1);

  // LSTM (len-sorted desc blocks; x pre-renormed from itn); hn -> A1[:,128:256]
  lstm_kernel<<<400, 512, 0, stream>>>(itn, seqs, Wcat, bias, lens, perm, A1);

  // feat = relu(A1 @ W1^T)
  gemm_bt_kernel<1><<<dim3(1, 200), 256, 0, stream>>>(A1, W1b, feat, 25600, 128, 256);
  set_cur_kernel<<<256, 256, 0, stream>>>(A1, cur_sidx, feat);

  // GAT layer 0
  gat_score_kernel<<<6400, 256, 0, stream>>>(feat, src0, dst0, idx0, sc0, m0, 25600);
  gat_agg_kernel  <<<12800,256, 0, stream>>>(feat, src0, dst0, sc0, m0, agg0, z0, 25600);
  gat_out_kernel  <<<2560, 128, 0, stream>>>(feat, idx0, agg0, z0, gW0, gb0, feat1, 2560);

  // GAT layer 1
  gat_score_kernel<<<1280, 256, 0, stream>>>(feat1, src1, dst1, idx1, sc1, m1, 5120);
  gat_agg_kernel  <<<2560, 256, 0, stream>>>(feat1, src1, dst1, sc1, m1, agg1, z1, 5120);
  gat_out_kernel  <<<512,  128, 0, stream>>>(feat1, idx1, agg1, z1, gW1, gb1, feat2, 512);

  // sr = concat(cur, feat2) @ W2^T  (bf16 out for logits GEMM)
  sr_kernel<<<512, 128, 0, stream>>>(A1, feat2, cur_sidx, W2, srb);

  // logits = srb @ itn^T
  gemm_bt_kernel<0><<<dim3(391, 4), 256, 0, stream>>>(srb, itn, out, 512, 50000, 128);
}